// Round 5
// baseline (2366.424 us; speedup 1.0000x reference)
//
#include <hip/hip_runtime.h>
#include <hip/hip_bf16.h>

#define NN 100000
#define NE 1600000
#define SW 136   // padded stride (shorts) for [64][128] bf16 weight tiles
#define ST 68    // padded stride (shorts) for [16][64] bf16 link tiles

typedef __attribute__((ext_vector_type(8))) short bf16x8;
typedef __attribute__((ext_vector_type(4))) float f32x4;

__device__ __forceinline__ unsigned short f2bf(float f) {
    union { float f; unsigned int u; } v; v.f = f;
    unsigned int u = v.u + 0x7fff + ((v.u >> 16) & 1);
    return (unsigned short)(u >> 16);
}
__device__ __forceinline__ float bf2f(unsigned short h) {
    union { unsigned int u; float f; } v; v.u = ((unsigned int)h) << 16;
    return v.f;
}
__device__ __forceinline__ float silu_f(float v) {
    return v / (1.0f + __expf(-v));
}

// ---------------- CSR build ----------------
__global__ void hist_kernel(const int* __restrict__ dst, int* __restrict__ counts) {
    int i = blockIdx.x * 256 + threadIdx.x;
    if (i < NE) atomicAdd(&counts[dst[i]], 1);
}

__global__ __launch_bounds__(1024) void scan_kernel(const int* __restrict__ counts,
                                                    int* __restrict__ rowptr,
                                                    int* __restrict__ cursor) {
    __shared__ int tsum[1024];
    const int T = 1024;
    int tid = threadIdx.x;
    const int per = (NN + T - 1) / T;
    int base = tid * per;
    int s = 0;
    for (int i = 0; i < per; ++i) {
        int idx = base + i;
        if (idx < NN) s += counts[idx];
    }
    tsum[tid] = s;
    __syncthreads();
    for (int off = 1; off < T; off <<= 1) {
        int v = tsum[tid];
        int add = (tid >= off) ? tsum[tid - off] : 0;
        __syncthreads();
        tsum[tid] = v + add;
        __syncthreads();
    }
    int run = (tid == 0) ? 0 : tsum[tid - 1];
    for (int i = 0; i < per; ++i) {
        int idx = base + i;
        if (idx < NN) {
            rowptr[idx] = run;
            cursor[idx] = run;
            run += counts[idx];
        }
    }
    if (tid == T - 1) rowptr[NN] = run;
}

__global__ void scatter_kernel(const int* __restrict__ src, const int* __restrict__ dst,
                               int* __restrict__ cursor, int* __restrict__ srcS) {
    int i = blockIdx.x * 256 + threadIdx.x;
    if (i < NE) {
        int pos = atomicAdd(&cursor[dst[i]], 1);
        srcS[pos] = src[i];
    }
}

// ---------------------------------------------------------------------------
// Edge kernel over CSR: one WAVE per dst node; msg_h accumulated in fp32
// registers across 16-edge chunks; one non-atomic store per node. No atomics.
// launch_bounds(256,3): ~168 VGPR cap — the loop-carried accumulators
// (macc/xacc/coord) must stay in registers (at (256,4)=128 cap they spilled:
// 2.5 GB scratch r/w, round 4). B2 fragments in LDS, not registers.
// ---------------------------------------------------------------------------
template <bool WRITE_X>
__global__ __launch_bounds__(256, 3) void edge2_kernel(
    const float4* __restrict__ x4,
    const unsigned short* __restrict__ hbf,
    const int* __restrict__ rowptr,
    const int* __restrict__ srcS,
    const float* __restrict__ ew1,   // [129,64]
    const float* __restrict__ eb1,
    const float* __restrict__ ew2,   // [64,64]
    const float* __restrict__ eb2,
    const float* __restrict__ cw1,   // [64,64]
    const float* __restrict__ cb1,
    const float* __restrict__ cw2,   // [64]
    unsigned short* __restrict__ h_nb,  // [N,64] bf16 out
    float4* __restrict__ xout)          // [N] out (WRITE_X only)
{
    __shared__ __align__(16) unsigned short w1T[64 * SW];      // B^T GEMM1
    __shared__ __align__(16) unsigned short w2T[64 * ST];      // B^T GEMM2
    __shared__ __align__(16) unsigned short c1T[64 * ST];      // B^T GEMM3
    __shared__ __align__(16) unsigned short tAll[4 * 16 * ST]; // per-wave link buf
    __shared__ float eb1s[64], eb2s[64], cb1s[64], cw2s[64], w1l[64];

    const int tid  = threadIdx.x;
    const int wave = tid >> 6;
    const int lane = tid & 63;
    const int quad = lane >> 4;
    const int l15  = lane & 15;

    for (int i = tid; i < 64 * 128; i += 256) {
        int n = i & 63, k = i >> 6;
        w1T[n * SW + k] = f2bf(ew1[k * 64 + n]);
    }
    for (int i = tid; i < 64 * 64; i += 256) {
        int n = i & 63, k = i >> 6;
        w2T[n * ST + k] = f2bf(ew2[k * 64 + n]);
    }
    if (WRITE_X) {
        for (int i = tid; i < 64 * 64; i += 256) {
            int n = i & 63, k = i >> 6;
            c1T[n * ST + k] = f2bf(cw1[k * 64 + n]);
        }
    }
    if (tid < 64) {
        eb1s[tid] = eb1[tid]; eb2s[tid] = eb2[tid]; cb1s[tid] = cb1[tid];
        cw2s[tid] = cw2[tid]; w1l[tid] = ew1[128 * 64 + tid];
    }
    __syncthreads();   // only barrier

    unsigned short* tW = tAll + wave * 16 * ST;
    const int gw = blockIdx.x * 4 + wave;
    const int nw = gridDim.x * 4;

    for (int n = gw; n < NN; n += nw) {
        const int segS = rowptr[n], segE = rowptr[n + 1];
        const float4 xn = x4[n];
        const unsigned short* pn = hbf + (size_t)n * 64 + quad * 8;
        bf16x8 a2 = *(const bf16x8*)(pn);
        bf16x8 a3 = *(const bf16x8*)(pn + 32);

        float macc[4][4];
#pragma unroll
        for (int nt = 0; nt < 4; ++nt)
#pragma unroll
            for (int r = 0; r < 4; ++r) macc[nt][r] = 0.f;
        float xacc[4] = {0.f, 0.f, 0.f, 0.f};

        for (int cs = segS; cs < segE; cs += 16) {
            int s = n; float rad = 0.f, xdx = 0.f, xdy = 0.f, xdz = 0.f;
            if (lane < 16) {
                int e = cs + lane;
                if (e < segE) {
                    s = srcS[e];
                    float4 xs = x4[s];
                    float dx = xs.x - xn.x;
                    float dy = xs.y - xn.y;
                    float dz = xs.z - xn.z;
                    rad = dx * dx + dy * dy + dz * dz;
                    float inv = 1.0f / (sqrtf(rad) + 1e-30f);
                    xdx = dx * inv; xdy = dy * inv; xdz = dz * inv;
                }
            }
            const int rowS = __shfl(s, l15);
            const unsigned short* ps = hbf + (size_t)rowS * 64 + quad * 8;
            bf16x8 a0 = *(const bf16x8*)(ps);
            bf16x8 a1 = *(const bf16x8*)(ps + 32);

            float radR[4]; float cxR[4], cyR[4], czR[4]; bool valR[4];
#pragma unroll
            for (int r = 0; r < 4; ++r) {
                int er = quad * 4 + r;
                radR[r] = __shfl(rad, er);
                valR[r] = (cs + er) < segE;
                if (WRITE_X) {
                    cxR[r] = __shfl(xdx, er);
                    cyR[r] = __shfl(xdy, er);
                    czR[r] = __shfl(xdz, er);
                }
            }

            // GEMM1: K=128 (cols 0..63 h[src], 64..127 h[dst])
            f32x4 acc[4];
#pragma unroll
            for (int nt = 0; nt < 4; ++nt) acc[nt] = (f32x4){0.f, 0.f, 0.f, 0.f};
            {
                const unsigned short* bBase = &w1T[l15 * SW + quad * 8];
#pragma unroll
                for (int nt = 0; nt < 4; ++nt) {
                    const unsigned short* bb = bBase + nt * 16 * SW;
                    acc[nt] = __builtin_amdgcn_mfma_f32_16x16x32_bf16(a0, *(const bf16x8*)(bb), acc[nt], 0, 0, 0);
                    acc[nt] = __builtin_amdgcn_mfma_f32_16x16x32_bf16(a1, *(const bf16x8*)(bb + 32), acc[nt], 0, 0, 0);
                    acc[nt] = __builtin_amdgcn_mfma_f32_16x16x32_bf16(a2, *(const bf16x8*)(bb + 64), acc[nt], 0, 0, 0);
                    acc[nt] = __builtin_amdgcn_mfma_f32_16x16x32_bf16(a3, *(const bf16x8*)(bb + 96), acc[nt], 0, 0, 0);
                }
            }
#pragma unroll
            for (int nt = 0; nt < 4; ++nt) {
                int col = nt * 16 + l15;
#pragma unroll
                for (int r = 0; r < 4; ++r) {
                    float v = acc[nt][r] + eb1s[col] + radR[r] * w1l[col];
                    tW[(quad * 4 + r) * ST + col] = f2bf(silu_f(v));
                }
            }
            // GEMM2: K=64 (B from LDS)
            f32x4 acc2[4];
#pragma unroll
            for (int nt = 0; nt < 4; ++nt) acc2[nt] = (f32x4){0.f, 0.f, 0.f, 0.f};
            {
                bf16x8 ax0 = *(const bf16x8*)&tW[l15 * ST + quad * 8];
                bf16x8 ax1 = *(const bf16x8*)&tW[l15 * ST + 32 + quad * 8];
                const unsigned short* bBase = &w2T[l15 * ST + quad * 8];
#pragma unroll
                for (int nt = 0; nt < 4; ++nt) {
                    const unsigned short* bb = bBase + nt * 16 * ST;
                    acc2[nt] = __builtin_amdgcn_mfma_f32_16x16x32_bf16(ax0, *(const bf16x8*)(bb), acc2[nt], 0, 0, 0);
                    acc2[nt] = __builtin_amdgcn_mfma_f32_16x16x32_bf16(ax1, *(const bf16x8*)(bb + 32), acc2[nt], 0, 0, 0);
                }
            }
#pragma unroll
            for (int nt = 0; nt < 4; ++nt) {
                int col = nt * 16 + l15;
#pragma unroll
                for (int r = 0; r < 4; ++r) {
                    float v = silu_f(acc2[nt][r] + eb2s[col]);
                    if (valR[r]) macc[nt][r] += v;
                    if (WRITE_X) tW[(quad * 4 + r) * ST + col] = f2bf(v);
                }
            }
            if (WRITE_X) {
                // GEMM3: K=64
                f32x4 acc3[4];
#pragma unroll
                for (int nt = 0; nt < 4; ++nt) acc3[nt] = (f32x4){0.f, 0.f, 0.f, 0.f};
                {
                    bf16x8 ax0 = *(const bf16x8*)&tW[l15 * ST + quad * 8];
                    bf16x8 ax1 = *(const bf16x8*)&tW[l15 * ST + 32 + quad * 8];
                    const unsigned short* bBase = &c1T[l15 * ST + quad * 8];
#pragma unroll
                    for (int nt = 0; nt < 4; ++nt) {
                        const unsigned short* bb = bBase + nt * 16 * ST;
                        acc3[nt] = __builtin_amdgcn_mfma_f32_16x16x32_bf16(ax0, *(const bf16x8*)(bb), acc3[nt], 0, 0, 0);
                        acc3[nt] = __builtin_amdgcn_mfma_f32_16x16x32_bf16(ax1, *(const bf16x8*)(bb + 32), acc3[nt], 0, 0, 0);
                    }
                }
                float part_[4] = {0.f, 0.f, 0.f, 0.f};
#pragma unroll
                for (int nt = 0; nt < 4; ++nt) {
                    int col = nt * 16 + l15;
#pragma unroll
                    for (int r = 0; r < 4; ++r)
                        part_[r] += silu_f(acc3[nt][r] + cb1s[col]) * cw2s[col];
                }
#pragma unroll
                for (int r = 0; r < 4; ++r) {
                    float p = part_[r];
                    p += __shfl_xor(p, 1);
                    p += __shfl_xor(p, 2);
                    p += __shfl_xor(p, 4);
                    p += __shfl_xor(p, 8);
                    if (valR[r]) {
                        float comp = (l15 == 0) ? cxR[r] : (l15 == 1) ? cyR[r] : czR[r];
                        xacc[r] += p * comp;   // meaningful for l15<3 only
                    }
                }
            }
        }
        // reduce msg accumulator over rows (r in-lane, quads via shfl) and store
#pragma unroll
        for (int nt = 0; nt < 4; ++nt) {
            float mm = macc[nt][0] + macc[nt][1] + macc[nt][2] + macc[nt][3];
            mm += __shfl_xor(mm, 16);
            mm += __shfl_xor(mm, 32);
            if (quad == 0) h_nb[(size_t)n * 64 + nt * 16 + l15] = f2bf(mm);
        }
        if (WRITE_X) {
            float xa = xacc[0] + xacc[1] + xacc[2] + xacc[3];
            xa += __shfl_xor(xa, 16);
            xa += __shfl_xor(xa, 32);
            if (quad == 0 && l15 < 3) {
                float d = fmaxf((float)(segE - segS), 1.0f);
                float base = (l15 == 0) ? xn.x : (l15 == 1) ? xn.y : xn.z;
                ((float*)&xout[n])[l15] = base + xa / d;
            }
        }
    }
}

// ---------------------------------------------------------------------------
// Node kernel: h_new = silu([h|h_nb]@NW1+nb1)@NW2+nb2 -> gelu -> LayerNorm.
// DO_HEAD: fuse final out = y@out_w+out_b (skip hbf store).
// ---------------------------------------------------------------------------
template <bool DO_HEAD>
__global__ __launch_bounds__(256, 4) void node_kernel(
    unsigned short* hbf,
    const unsigned short* __restrict__ h_nb,   // [N,64] bf16
    const float* __restrict__ nw1,
    const float* __restrict__ nb1,
    const float* __restrict__ nw2,
    const float* __restrict__ nb2,
    const float* __restrict__ ln_g,
    const float* __restrict__ ln_b,
    const float* __restrict__ out_w,  // [64,32]
    const float* __restrict__ out_b,  // [32]
    float* __restrict__ out)          // [N,32]
{
    __shared__ __align__(16) unsigned short w1T[64 * SW];
    __shared__ __align__(16) unsigned short w2T[64 * ST];
    __shared__ __align__(16) unsigned short tAll[4 * 16 * ST];
    __shared__ float nb1s[64], nb2s[64], gs[64], bs[64], obs[32];

    const int tid  = threadIdx.x;
    const int wave = tid >> 6;
    const int lane = tid & 63;
    const int quad = lane >> 4;
    const int l15  = lane & 15;

    for (int i = tid; i < 64 * 128; i += 256) {
        int n = i & 63, k = i >> 6;
        w1T[n * SW + k] = f2bf(nw1[k * 64 + n]);
    }
    for (int i = tid; i < 64 * 64; i += 256) {
        int n = i & 63, k = i >> 6;
        w2T[n * ST + k] = f2bf(nw2[k * 64 + n]);
    }
    if (tid < 64) {
        nb1s[tid] = nb1[tid]; nb2s[tid] = nb2[tid];
        gs[tid] = ln_g[tid]; bs[tid] = ln_b[tid];
        if (DO_HEAD && tid < 32) obs[tid] = out_b[tid];
    }
    bf16x8 b3[2][2];
    if (DO_HEAD) {
#pragma unroll
        for (int ks = 0; ks < 2; ++ks)
#pragma unroll
            for (int nt = 0; nt < 2; ++nt) {
#pragma unroll
                for (int j = 0; j < 8; ++j) {
                    int k = ks * 32 + quad * 8 + j;
                    ((unsigned short*)&b3[ks][nt])[j] = f2bf(out_w[k * 32 + nt * 16 + l15]);
                }
            }
    }
    __syncthreads();

    unsigned short* tW = tAll + wave * 16 * ST;

    for (int t = blockIdx.x * 4 + wave; t < NN / 16; t += gridDim.x * 4) {
        const int n0 = t * 16;
        const int myRow = n0 + l15;
        const unsigned short* ph = hbf + (size_t)myRow * 64 + quad * 8;
        bf16x8 a0 = *(const bf16x8*)(ph);
        bf16x8 a1 = *(const bf16x8*)(ph + 32);
        const unsigned short* pb = h_nb + (size_t)myRow * 64 + quad * 8;
        bf16x8 a2 = *(const bf16x8*)(pb);
        bf16x8 a3 = *(const bf16x8*)(pb + 32);

        f32x4 acc[4];
#pragma unroll
        for (int nt = 0; nt < 4; ++nt) acc[nt] = (f32x4){0.f, 0.f, 0.f, 0.f};
        {
            const unsigned short* bBase = &w1T[l15 * SW + quad * 8];
#pragma unroll
            for (int nt = 0; nt < 4; ++nt) {
                const unsigned short* bb = bBase + nt * 16 * SW;
                acc[nt] = __builtin_amdgcn_mfma_f32_16x16x32_bf16(a0, *(const bf16x8*)(bb), acc[nt], 0, 0, 0);
                acc[nt] = __builtin_amdgcn_mfma_f32_16x16x32_bf16(a1, *(const bf16x8*)(bb + 32), acc[nt], 0, 0, 0);
                acc[nt] = __builtin_amdgcn_mfma_f32_16x16x32_bf16(a2, *(const bf16x8*)(bb + 64), acc[nt], 0, 0, 0);
                acc[nt] = __builtin_amdgcn_mfma_f32_16x16x32_bf16(a3, *(const bf16x8*)(bb + 96), acc[nt], 0, 0, 0);
            }
        }
#pragma unroll
        for (int nt = 0; nt < 4; ++nt) {
            int col = nt * 16 + l15;
#pragma unroll
            for (int r = 0; r < 4; ++r) {
                float v = acc[nt][r] + nb1s[col];
                tW[(quad * 4 + r) * ST + col] = f2bf(silu_f(v));
            }
        }
        f32x4 acc2[4];
#pragma unroll
        for (int nt = 0; nt < 4; ++nt) acc2[nt] = (f32x4){0.f, 0.f, 0.f, 0.f};
        {
            bf16x8 ax0 = *(const bf16x8*)&tW[l15 * ST + quad * 8];
            bf16x8 ax1 = *(const bf16x8*)&tW[l15 * ST + 32 + quad * 8];
            const unsigned short* bBase = &w2T[l15 * ST + quad * 8];
#pragma unroll
            for (int nt = 0; nt < 4; ++nt) {
                const unsigned short* bb = bBase + nt * 16 * ST;
                acc2[nt] = __builtin_amdgcn_mfma_f32_16x16x32_bf16(ax0, *(const bf16x8*)(bb), acc2[nt], 0, 0, 0);
                acc2[nt] = __builtin_amdgcn_mfma_f32_16x16x32_bf16(ax1, *(const bf16x8*)(bb + 32), acc2[nt], 0, 0, 0);
            }
        }
        float vals[4][4];
        float sum[4] = {0.f, 0.f, 0.f, 0.f}, ss[4] = {0.f, 0.f, 0.f, 0.f};
#pragma unroll
        for (int nt = 0; nt < 4; ++nt) {
            int col = nt * 16 + l15;
#pragma unroll
            for (int r = 0; r < 4; ++r) {
                float v = acc2[nt][r] + nb2s[col];
                float g = 0.5f * v * (1.0f + erff(v * 0.70710678118654752f));
                vals[nt][r] = g;
                sum[r] += g;
                ss[r] += g * g;
            }
        }
#pragma unroll
        for (int r = 0; r < 4; ++r) {
            float s1 = sum[r], s2 = ss[r];
            s1 += __shfl_xor(s1, 1); s2 += __shfl_xor(s2, 1);
            s1 += __shfl_xor(s1, 2); s2 += __shfl_xor(s2, 2);
            s1 += __shfl_xor(s1, 4); s2 += __shfl_xor(s2, 4);
            s1 += __shfl_xor(s1, 8); s2 += __shfl_xor(s2, 8);
            sum[r] = s1; ss[r] = s2;
        }
#pragma unroll
        for (int r = 0; r < 4; ++r) {
            float mean = sum[r] * (1.0f / 64.0f);
            float var  = ss[r] * (1.0f / 64.0f) - mean * mean;
            float rstd = rsqrtf(var + 1e-5f);
            int n = n0 + quad * 4 + r;
#pragma unroll
            for (int nt = 0; nt < 4; ++nt) {
                int col = nt * 16 + l15;
                float y = (vals[nt][r] - mean) * rstd * gs[col] + bs[col];
                if (DO_HEAD) tW[(quad * 4 + r) * ST + col] = f2bf(y);
                else hbf[(size_t)n * 64 + col] = f2bf(y);
            }
        }
        if (DO_HEAD) {
            f32x4 accH[2];
#pragma unroll
            for (int nt = 0; nt < 2; ++nt) accH[nt] = (f32x4){0.f, 0.f, 0.f, 0.f};
            bf16x8 ax0 = *(const bf16x8*)&tW[l15 * ST + quad * 8];
            bf16x8 ax1 = *(const bf16x8*)&tW[l15 * ST + 32 + quad * 8];
#pragma unroll
            for (int nt = 0; nt < 2; ++nt) {
                accH[nt] = __builtin_amdgcn_mfma_f32_16x16x32_bf16(ax0, b3[0][nt], accH[nt], 0, 0, 0);
                accH[nt] = __builtin_amdgcn_mfma_f32_16x16x32_bf16(ax1, b3[1][nt], accH[nt], 0, 0, 0);
            }
#pragma unroll
            for (int nt = 0; nt < 2; ++nt) {
                int col = nt * 16 + l15;
#pragma unroll
                for (int r = 0; r < 4; ++r)
                    out[(size_t)(n0 + quad * 4 + r) * 32 + col] = accH[nt][r] + obs[col];
            }
        }
    }
}

__global__ void init_h(const float* __restrict__ nf, unsigned short* __restrict__ hbf) {
    int i = blockIdx.x * 256 + threadIdx.x;
    if (i < NN * 64) hbf[i] = f2bf(nf[i]);
}
__global__ void init_x(const float* __restrict__ xyz, float4* __restrict__ x4) {
    int n = blockIdx.x * 256 + threadIdx.x;
    if (n < NN) {
        float4 v;
        v.x = xyz[n * 3 + 0]; v.y = xyz[n * 3 + 1]; v.z = xyz[n * 3 + 2]; v.w = 0.f;
        x4[n] = v;
    }
}

extern "C" void kernel_launch(void* const* d_in, const int* in_sizes, int n_in,
                              void* d_out, int out_size, void* d_ws, size_t ws_size,
                              hipStream_t stream)
{
    const float* node_feat = (const float*)d_in[0];
    const float* xyz   = (const float*)d_in[1];
    const int*   src   = (const int*)d_in[2];
    const int*   dst   = (const int*)d_in[3];
    const float* ew1   = (const float*)d_in[4];
    const float* eb1   = (const float*)d_in[5];
    const float* ew2   = (const float*)d_in[6];
    const float* eb2   = (const float*)d_in[7];
    const float* cw1   = (const float*)d_in[8];
    const float* cb1   = (const float*)d_in[9];
    const float* cw2   = (const float*)d_in[10];
    const float* nw1   = (const float*)d_in[11];
    const float* nb1   = (const float*)d_in[12];
    const float* nw2   = (const float*)d_in[13];
    const float* nb2   = (const float*)d_in[14];
    const float* ln_g  = (const float*)d_in[15];
    const float* ln_b  = (const float*)d_in[16];
    const float* out_w = (const float*)d_in[17];
    const float* out_b = (const float*)d_in[18];
    float* out = (float*)d_out;

    char* ws = (char*)d_ws;
    unsigned short* h_nb = (unsigned short*)ws;  ws += (size_t)NN * 64 * 2;
    unsigned short* hbf  = (unsigned short*)ws;  ws += (size_t)NN * 64 * 2;
    float4* xA   = (float4*)ws;                  ws += (size_t)NN * 16;
    float4* xB   = (float4*)ws;                  ws += (size_t)NN * 16;
    int* rowptr  = (int*)ws;                     ws += (size_t)(NN + 1) * 4;
    int* counts  = (int*)ws;                     ws += (size_t)NN * 4;   // reused as cursor
    int* srcS    = (int*)ws;                     ws += (size_t)NE * 4;

    hipMemsetAsync(counts, 0, (size_t)NN * 4, stream);
    init_h<<<(NN * 64 + 255) / 256, 256, 0, stream>>>(node_feat, hbf);
    init_x<<<(NN + 255) / 256, 256, 0, stream>>>(xyz, xA);
    hist_kernel<<<(NE + 255) / 256, 256, 0, stream>>>(dst, counts);
    scan_kernel<<<1, 1024, 0, stream>>>(counts, rowptr, counts);
    scatter_kernel<<<(NE + 255) / 256, 256, 0, stream>>>(src, dst, counts, srcS);

    // layer 0 (writes x for layer 1)
    edge2_kernel<true><<<1024, 256, 0, stream>>>(
        xA, hbf, rowptr, srcS,
        ew1, eb1, ew2, eb2, cw1, cb1, cw2, h_nb, xB);
    node_kernel<false><<<1024, 256, 0, stream>>>(
        hbf, h_nb, nw1, nb1, nw2, nb2, ln_g, ln_b, out_w, out_b, out);

    // layer 1 (x output dead -> no coord head; head fused into node kernel)
    edge2_kernel<false><<<1024, 256, 0, stream>>>(
        xB, hbf, rowptr, srcS,
        ew1 + 129 * 64, eb1 + 64, ew2 + 64 * 64, eb2 + 64,
        cw1 + 64 * 64, cb1 + 64, cw2 + 64, h_nb, nullptr);
    node_kernel<true><<<1024, 256, 0, stream>>>(
        hbf, h_nb, nw1 + 128 * 64, nb1 + 64, nw2 + 64 * 64, nb2 + 64,
        ln_g, ln_b, out_w, out_b, out);
}

// Round 6
// 1478.773 us; speedup vs baseline: 1.6003x; 1.6003x over previous
//
#include <hip/hip_runtime.h>
#include <hip/hip_bf16.h>

#define NN 100000
#define NE 1600000
#define SW 136   // padded stride (shorts) for [64][128] bf16 weight tiles
#define ST 68    // padded stride (shorts) for [16][64] bf16 link tiles

typedef __attribute__((ext_vector_type(8))) short bf16x8;
typedef __attribute__((ext_vector_type(4))) float f32x4;

__device__ __forceinline__ unsigned short f2bf(float f) {
    union { float f; unsigned int u; } v; v.f = f;
    unsigned int u = v.u + 0x7fff + ((v.u >> 16) & 1);
    return (unsigned short)(u >> 16);
}
__device__ __forceinline__ float bf2f(unsigned short h) {
    union { unsigned int u; float f; } v; v.u = ((unsigned int)h) << 16;
    return v.f;
}
__device__ __forceinline__ float silu_f(float v) {
    return v / (1.0f + __expf(-v));
}

// ---------------- CSR + chunk-table build ----------------
__global__ void hist_kernel(const int* __restrict__ dst, int* __restrict__ counts) {
    int i = blockIdx.x * 256 + threadIdx.x;
    if (i < NE) atomicAdd(&counts[dst[i]], 1);
}

// single block: exclusive scans of counts (-> rowptr,cursor) and ceil(counts/16) (-> chunkPtr)
__global__ __launch_bounds__(1024) void scan_kernel(const int* __restrict__ counts,
                                                    int* __restrict__ rowptr,
                                                    int* __restrict__ cursor,
                                                    int* __restrict__ chunkPtr) {
    __shared__ int tsum[1024], csum[1024];
    const int T = 1024;
    int tid = threadIdx.x;
    const int per = (NN + T - 1) / T;
    int base = tid * per;
    int s = 0, c = 0;
    for (int i = 0; i < per; ++i) {
        int idx = base + i;
        if (idx < NN) { int v = counts[idx]; s += v; c += (v + 15) >> 4; }
    }
    tsum[tid] = s; csum[tid] = c;
    __syncthreads();
    for (int off = 1; off < T; off <<= 1) {
        int v = tsum[tid], w = csum[tid];
        int av = (tid >= off) ? tsum[tid - off] : 0;
        int aw = (tid >= off) ? csum[tid - off] : 0;
        __syncthreads();
        tsum[tid] = v + av; csum[tid] = w + aw;
        __syncthreads();
    }
    int run  = (tid == 0) ? 0 : tsum[tid - 1];
    int crun = (tid == 0) ? 0 : csum[tid - 1];
    for (int i = 0; i < per; ++i) {
        int idx = base + i;
        if (idx < NN) {
            int v = counts[idx];
            rowptr[idx] = run; cursor[idx] = run; chunkPtr[idx] = crun;
            run += v; crun += (v + 15) >> 4;
        }
    }
    if (tid == T - 1) { rowptr[NN] = run; chunkPtr[NN] = crun; }
}

__global__ void scatter_kernel(const int* __restrict__ src, const int* __restrict__ dst,
                               int* __restrict__ cursor, int* __restrict__ srcS) {
    int i = blockIdx.x * 256 + threadIdx.x;
    if (i < NE) {
        int pos = atomicAdd(&cursor[dst[i]], 1);
        srcS[pos] = src[i];
    }
}

__global__ void fill_chunks(const int* __restrict__ rowptr, const int* __restrict__ chunkPtr,
                            int2* __restrict__ chunkTbl) {
    int n = blockIdx.x * 256 + threadIdx.x;
    if (n < NN) {
        int s = rowptr[n], e = rowptr[n + 1];
        int b = chunkPtr[n];
        for (int cs = s, i = 0; cs < e; cs += 16, ++i)
            chunkTbl[b + i] = make_int2(n, cs);
    }
}

// ---------------------------------------------------------------------------
// Edge kernel, chunk-parallel and STATELESS per chunk (nothing loop-carried
// except the induction var): per 16-edge chunk (single dst node), run the
// GEMM chain, reduce msg over rows in-wave, issue 64 fp32 atomics to h_neigh
// (+3 to x_sum). Loop-carried accumulators caused 4 GB of scratch spill
// traffic in rounds 4/5 — keep this body stateless.
// MFMA 16x16x32 bf16. A[m=l15][k=quad*8+j]; C/D: col=l15+16nt, row=quad*4+r
// ---------------------------------------------------------------------------
template <bool WRITE_X>
__global__ __launch_bounds__(256, 3) void edge3_kernel(
    const float4* __restrict__ x4,
    const unsigned short* __restrict__ hbf,
    const int* __restrict__ rowptr,
    const int* __restrict__ srcS,
    const int2* __restrict__ chunkTbl,
    const int* __restrict__ chunkCnt,   // = &chunkPtr[NN]
    const float* __restrict__ ew1,   // [129,64]
    const float* __restrict__ eb1,
    const float* __restrict__ ew2,   // [64,64]
    const float* __restrict__ eb2,
    const float* __restrict__ cw1,   // [64,64]
    const float* __restrict__ cb1,
    const float* __restrict__ cw2,   // [64]
    float* __restrict__ h_neigh,     // [N,64] fp32 (pre-zeroed)
    float* __restrict__ x_sum)       // [N,3] fp32 (pre-zeroed, WRITE_X only)
{
    __shared__ __align__(16) unsigned short w1T[64 * SW];      // B^T GEMM1
    __shared__ __align__(16) unsigned short w2T[64 * ST];      // B^T GEMM2
    __shared__ __align__(16) unsigned short c1T[64 * ST];      // B^T GEMM3
    __shared__ __align__(16) unsigned short tAll[4 * 16 * ST]; // per-wave link buf
    __shared__ float eb1s[64], eb2s[64], cb1s[64], cw2s[64], w1l[64];

    const int tid  = threadIdx.x;
    const int wave = tid >> 6;
    const int lane = tid & 63;
    const int quad = lane >> 4;
    const int l15  = lane & 15;

    for (int i = tid; i < 64 * 128; i += 256) {
        int n = i & 63, k = i >> 6;
        w1T[n * SW + k] = f2bf(ew1[k * 64 + n]);
    }
    for (int i = tid; i < 64 * 64; i += 256) {
        int n = i & 63, k = i >> 6;
        w2T[n * ST + k] = f2bf(ew2[k * 64 + n]);
    }
    if (WRITE_X) {
        for (int i = tid; i < 64 * 64; i += 256) {
            int n = i & 63, k = i >> 6;
            c1T[n * ST + k] = f2bf(cw1[k * 64 + n]);
        }
    }
    if (tid < 64) {
        eb1s[tid] = eb1[tid]; eb2s[tid] = eb2[tid]; cb1s[tid] = cb1[tid];
        cw2s[tid] = cw2[tid]; w1l[tid] = ew1[128 * 64 + tid];
    }
    __syncthreads();   // only barrier

    unsigned short* tW = tAll + wave * 16 * ST;
    const int C  = chunkCnt[0];
    const int gw = blockIdx.x * 4 + wave;
    const int nw = gridDim.x * 4;

    for (int idx = gw; idx < C; idx += nw) {
        const int2 ck = chunkTbl[idx];
        const int n = ck.x, cs = ck.y;
        const int segE = rowptr[n + 1];

        // lanes 0..15: edge metadata
        int s = n; float rad = 0.f, xdx = 0.f, xdy = 0.f, xdz = 0.f;
        if (lane < 16) {
            int e = cs + lane;
            if (e < segE) {
                s = srcS[e];
                float4 xs = x4[s];
                float4 xn = x4[n];
                float dx = xs.x - xn.x;
                float dy = xs.y - xn.y;
                float dz = xs.z - xn.z;
                rad = dx * dx + dy * dy + dz * dz;
                float inv = 1.0f / (sqrtf(rad) + 1e-30f);
                xdx = dx * inv; xdy = dy * inv; xdz = dz * inv;
            }
        }
        const int rowS = __shfl(s, l15);
        const unsigned short* ps = hbf + (size_t)rowS * 64 + quad * 8;
        bf16x8 a0 = *(const bf16x8*)(ps);
        bf16x8 a1 = *(const bf16x8*)(ps + 32);
        const unsigned short* pn = hbf + (size_t)n * 64 + quad * 8;
        bf16x8 a2 = *(const bf16x8*)(pn);
        bf16x8 a3 = *(const bf16x8*)(pn + 32);

        float radR[4]; float cxR[4], cyR[4], czR[4]; bool valR[4];
#pragma unroll
        for (int r = 0; r < 4; ++r) {
            int er = quad * 4 + r;
            radR[r] = __shfl(rad, er);
            valR[r] = (cs + er) < segE;
            if (WRITE_X) {
                cxR[r] = __shfl(xdx, er);
                cyR[r] = __shfl(xdy, er);
                czR[r] = __shfl(xdz, er);
            }
        }

        // GEMM1: K=128 (cols 0..63 h[src], 64..127 h[dst])
        f32x4 acc[4];
#pragma unroll
        for (int nt = 0; nt < 4; ++nt) acc[nt] = (f32x4){0.f, 0.f, 0.f, 0.f};
        {
            const unsigned short* bBase = &w1T[l15 * SW + quad * 8];
#pragma unroll
            for (int nt = 0; nt < 4; ++nt) {
                const unsigned short* bb = bBase + nt * 16 * SW;
                acc[nt] = __builtin_amdgcn_mfma_f32_16x16x32_bf16(a0, *(const bf16x8*)(bb), acc[nt], 0, 0, 0);
                acc[nt] = __builtin_amdgcn_mfma_f32_16x16x32_bf16(a1, *(const bf16x8*)(bb + 32), acc[nt], 0, 0, 0);
                acc[nt] = __builtin_amdgcn_mfma_f32_16x16x32_bf16(a2, *(const bf16x8*)(bb + 64), acc[nt], 0, 0, 0);
                acc[nt] = __builtin_amdgcn_mfma_f32_16x16x32_bf16(a3, *(const bf16x8*)(bb + 96), acc[nt], 0, 0, 0);
            }
        }
#pragma unroll
        for (int nt = 0; nt < 4; ++nt) {
            int col = nt * 16 + l15;
#pragma unroll
            for (int r = 0; r < 4; ++r) {
                float v = acc[nt][r] + eb1s[col] + radR[r] * w1l[col];
                tW[(quad * 4 + r) * ST + col] = f2bf(silu_f(v));
            }
        }
        // GEMM2: K=64
        f32x4 acc2[4];
#pragma unroll
        for (int nt = 0; nt < 4; ++nt) acc2[nt] = (f32x4){0.f, 0.f, 0.f, 0.f};
        {
            bf16x8 ax0 = *(const bf16x8*)&tW[l15 * ST + quad * 8];
            bf16x8 ax1 = *(const bf16x8*)&tW[l15 * ST + 32 + quad * 8];
            const unsigned short* bBase = &w2T[l15 * ST + quad * 8];
#pragma unroll
            for (int nt = 0; nt < 4; ++nt) {
                const unsigned short* bb = bBase + nt * 16 * ST;
                acc2[nt] = __builtin_amdgcn_mfma_f32_16x16x32_bf16(ax0, *(const bf16x8*)(bb), acc2[nt], 0, 0, 0);
                acc2[nt] = __builtin_amdgcn_mfma_f32_16x16x32_bf16(ax1, *(const bf16x8*)(bb + 32), acc2[nt], 0, 0, 0);
            }
        }
        // epilogue2: silu -> msg; per-chunk column reduce -> atomics; tW for GEMM3
#pragma unroll
        for (int nt = 0; nt < 4; ++nt) {
            int col = nt * 16 + l15;
            float colsum = 0.f;
#pragma unroll
            for (int r = 0; r < 4; ++r) {
                float v = silu_f(acc2[nt][r] + eb2s[col]);
                if (valR[r]) colsum += v;
                if (WRITE_X) tW[(quad * 4 + r) * ST + col] = f2bf(v);
            }
            colsum += __shfl_xor(colsum, 16);
            colsum += __shfl_xor(colsum, 32);
            if (quad == 0) atomicAdd(&h_neigh[(size_t)n * 64 + col], colsum);
        }
        if (WRITE_X) {
            // GEMM3: K=64
            f32x4 acc3[4];
#pragma unroll
            for (int nt = 0; nt < 4; ++nt) acc3[nt] = (f32x4){0.f, 0.f, 0.f, 0.f};
            {
                bf16x8 ax0 = *(const bf16x8*)&tW[l15 * ST + quad * 8];
                bf16x8 ax1 = *(const bf16x8*)&tW[l15 * ST + 32 + quad * 8];
                const unsigned short* bBase = &c1T[l15 * ST + quad * 8];
#pragma unroll
                for (int nt = 0; nt < 4; ++nt) {
                    const unsigned short* bb = bBase + nt * 16 * ST;
                    acc3[nt] = __builtin_amdgcn_mfma_f32_16x16x32_bf16(ax0, *(const bf16x8*)(bb), acc3[nt], 0, 0, 0);
                    acc3[nt] = __builtin_amdgcn_mfma_f32_16x16x32_bf16(ax1, *(const bf16x8*)(bb + 32), acc3[nt], 0, 0, 0);
                }
            }
            float part_[4] = {0.f, 0.f, 0.f, 0.f};
#pragma unroll
            for (int nt = 0; nt < 4; ++nt) {
                int col = nt * 16 + l15;
#pragma unroll
                for (int r = 0; r < 4; ++r)
                    part_[r] += silu_f(acc3[nt][r] + cb1s[col]) * cw2s[col];
            }
            float xc = 0.f;
#pragma unroll
            for (int r = 0; r < 4; ++r) {
                float p = part_[r];
                p += __shfl_xor(p, 1);
                p += __shfl_xor(p, 2);
                p += __shfl_xor(p, 4);
                p += __shfl_xor(p, 8);
                if (valR[r]) {
                    float comp = (l15 == 0) ? cxR[r] : (l15 == 1) ? cyR[r] : czR[r];
                    xc += p * comp;
                }
            }
            xc += __shfl_xor(xc, 16);
            xc += __shfl_xor(xc, 32);
            if (quad == 0 && l15 < 3)
                atomicAdd(&x_sum[(size_t)n * 3 + l15], xc);
        }
    }
}

__global__ void xupd(const float* __restrict__ x_sum, const int* __restrict__ rowptr,
                     const float4* __restrict__ xin, float4* __restrict__ xout) {
    int n = blockIdx.x * 256 + threadIdx.x;
    if (n < NN) {
        float d = (float)(rowptr[n + 1] - rowptr[n]);
        float id = 1.0f / fmaxf(d, 1.0f);
        float4 v = xin[n];
        v.x += x_sum[n * 3 + 0] * id;
        v.y += x_sum[n * 3 + 1] * id;
        v.z += x_sum[n * 3 + 2] * id;
        v.w = 0.f;
        xout[n] = v;
    }
}

// ---------------------------------------------------------------------------
// Node kernel: h_new = silu([h|h_neigh]@NW1+nb1)@NW2+nb2 -> gelu -> LayerNorm.
// DO_HEAD: fuse final out = y@out_w+out_b (skip hbf store).
// ---------------------------------------------------------------------------
template <bool DO_HEAD>
__global__ __launch_bounds__(256, 4) void node_kernel(
    unsigned short* hbf,
    const float* __restrict__ h_nb,   // [N,64] fp32
    const float* __restrict__ nw1,
    const float* __restrict__ nb1,
    const float* __restrict__ nw2,
    const float* __restrict__ nb2,
    const float* __restrict__ ln_g,
    const float* __restrict__ ln_b,
    const float* __restrict__ out_w,  // [64,32]
    const float* __restrict__ out_b,  // [32]
    float* __restrict__ out)          // [N,32]
{
    __shared__ __align__(16) unsigned short w1T[64 * SW];
    __shared__ __align__(16) unsigned short w2T[64 * ST];
    __shared__ __align__(16) unsigned short tAll[4 * 16 * ST];
    __shared__ float nb1s[64], nb2s[64], gs[64], bs[64], obs[32];

    const int tid  = threadIdx.x;
    const int wave = tid >> 6;
    const int lane = tid & 63;
    const int quad = lane >> 4;
    const int l15  = lane & 15;

    for (int i = tid; i < 64 * 128; i += 256) {
        int n = i & 63, k = i >> 6;
        w1T[n * SW + k] = f2bf(nw1[k * 64 + n]);
    }
    for (int i = tid; i < 64 * 64; i += 256) {
        int n = i & 63, k = i >> 6;
        w2T[n * ST + k] = f2bf(nw2[k * 64 + n]);
    }
    if (tid < 64) {
        nb1s[tid] = nb1[tid]; nb2s[tid] = nb2[tid];
        gs[tid] = ln_g[tid]; bs[tid] = ln_b[tid];
        if (DO_HEAD && tid < 32) obs[tid] = out_b[tid];
    }
    bf16x8 b3[2][2];
    if (DO_HEAD) {
#pragma unroll
        for (int ks = 0; ks < 2; ++ks)
#pragma unroll
            for (int nt = 0; nt < 2; ++nt) {
#pragma unroll
                for (int j = 0; j < 8; ++j) {
                    int k = ks * 32 + quad * 8 + j;
                    ((unsigned short*)&b3[ks][nt])[j] = f2bf(out_w[k * 32 + nt * 16 + l15]);
                }
            }
    }
    __syncthreads();

    unsigned short* tW = tAll + wave * 16 * ST;

    for (int t = blockIdx.x * 4 + wave; t < NN / 16; t += gridDim.x * 4) {
        const int n0 = t * 16;
        const int myRow = n0 + l15;
        const unsigned short* ph = hbf + (size_t)myRow * 64 + quad * 8;
        bf16x8 a0 = *(const bf16x8*)(ph);
        bf16x8 a1 = *(const bf16x8*)(ph + 32);
        bf16x8 a2, a3;
        {
            const float* pb = h_nb + (size_t)myRow * 64 + quad * 8;
            float4 v0 = *(const float4*)(pb);
            float4 v1 = *(const float4*)(pb + 4);
            float4 v2 = *(const float4*)(pb + 32);
            float4 v3 = *(const float4*)(pb + 36);
            unsigned short* pa2 = (unsigned short*)&a2;
            unsigned short* pa3 = (unsigned short*)&a3;
            pa2[0] = f2bf(v0.x); pa2[1] = f2bf(v0.y); pa2[2] = f2bf(v0.z); pa2[3] = f2bf(v0.w);
            pa2[4] = f2bf(v1.x); pa2[5] = f2bf(v1.y); pa2[6] = f2bf(v1.z); pa2[7] = f2bf(v1.w);
            pa3[0] = f2bf(v2.x); pa3[1] = f2bf(v2.y); pa3[2] = f2bf(v2.z); pa3[3] = f2bf(v2.w);
            pa3[4] = f2bf(v3.x); pa3[5] = f2bf(v3.y); pa3[6] = f2bf(v3.z); pa3[7] = f2bf(v3.w);
        }

        f32x4 acc[4];
#pragma unroll
        for (int nt = 0; nt < 4; ++nt) acc[nt] = (f32x4){0.f, 0.f, 0.f, 0.f};
        {
            const unsigned short* bBase = &w1T[l15 * SW + quad * 8];
#pragma unroll
            for (int nt = 0; nt < 4; ++nt) {
                const unsigned short* bb = bBase + nt * 16 * SW;
                acc[nt] = __builtin_amdgcn_mfma_f32_16x16x32_bf16(a0, *(const bf16x8*)(bb), acc[nt], 0, 0, 0);
                acc[nt] = __builtin_amdgcn_mfma_f32_16x16x32_bf16(a1, *(const bf16x8*)(bb + 32), acc[nt], 0, 0, 0);
                acc[nt] = __builtin_amdgcn_mfma_f32_16x16x32_bf16(a2, *(const bf16x8*)(bb + 64), acc[nt], 0, 0, 0);
                acc[nt] = __builtin_amdgcn_mfma_f32_16x16x32_bf16(a3, *(const bf16x8*)(bb + 96), acc[nt], 0, 0, 0);
            }
        }
#pragma unroll
        for (int nt = 0; nt < 4; ++nt) {
            int col = nt * 16 + l15;
#pragma unroll
            for (int r = 0; r < 4; ++r) {
                float v = acc[nt][r] + nb1s[col];
                tW[(quad * 4 + r) * ST + col] = f2bf(silu_f(v));
            }
        }
        f32x4 acc2[4];
#pragma unroll
        for (int nt = 0; nt < 4; ++nt) acc2[nt] = (f32x4){0.f, 0.f, 0.f, 0.f};
        {
            bf16x8 ax0 = *(const bf16x8*)&tW[l15 * ST + quad * 8];
            bf16x8 ax1 = *(const bf16x8*)&tW[l15 * ST + 32 + quad * 8];
            const unsigned short* bBase = &w2T[l15 * ST + quad * 8];
#pragma unroll
            for (int nt = 0; nt < 4; ++nt) {
                const unsigned short* bb = bBase + nt * 16 * ST;
                acc2[nt] = __builtin_amdgcn_mfma_f32_16x16x32_bf16(ax0, *(const bf16x8*)(bb), acc2[nt], 0, 0, 0);
                acc2[nt] = __builtin_amdgcn_mfma_f32_16x16x32_bf16(ax1, *(const bf16x8*)(bb + 32), acc2[nt], 0, 0, 0);
            }
        }
        float vals[4][4];
        float sum[4] = {0.f, 0.f, 0.f, 0.f}, ss[4] = {0.f, 0.f, 0.f, 0.f};
#pragma unroll
        for (int nt = 0; nt < 4; ++nt) {
            int col = nt * 16 + l15;
#pragma unroll
            for (int r = 0; r < 4; ++r) {
                float v = acc2[nt][r] + nb2s[col];
                float g = 0.5f * v * (1.0f + erff(v * 0.70710678118654752f));
                vals[nt][r] = g;
                sum[r] += g;
                ss[r] += g * g;
            }
        }
#pragma unroll
        for (int r = 0; r < 4; ++r) {
            float s1 = sum[r], s2 = ss[r];
            s1 += __shfl_xor(s1, 1); s2 += __shfl_xor(s2, 1);
            s1 += __shfl_xor(s1, 2); s2 += __shfl_xor(s2, 2);
            s1 += __shfl_xor(s1, 4); s2 += __shfl_xor(s2, 4);
            s1 += __shfl_xor(s1, 8); s2 += __shfl_xor(s2, 8);
            sum[r] = s1; ss[r] = s2;
        }
#pragma unroll
        for (int r = 0; r < 4; ++r) {
            float mean = sum[r] * (1.0f / 64.0f);
            float var  = ss[r] * (1.0f / 64.0f) - mean * mean;
            float rstd = rsqrtf(var + 1e-5f);
            int n = n0 + quad * 4 + r;
#pragma unroll
            for (int nt = 0; nt < 4; ++nt) {
                int col = nt * 16 + l15;
                float y = (vals[nt][r] - mean) * rstd * gs[col] + bs[col];
                if (DO_HEAD) tW[(quad * 4 + r) * ST + col] = f2bf(y);
                else hbf[(size_t)n * 64 + col] = f2bf(y);
            }
        }
        if (DO_HEAD) {
            f32x4 accH[2];
#pragma unroll
            for (int nt = 0; nt < 2; ++nt) accH[nt] = (f32x4){0.f, 0.f, 0.f, 0.f};
            bf16x8 ax0 = *(const bf16x8*)&tW[l15 * ST + quad * 8];
            bf16x8 ax1 = *(const bf16x8*)&tW[l15 * ST + 32 + quad * 8];
#pragma unroll
            for (int nt = 0; nt < 2; ++nt) {
                accH[nt] = __builtin_amdgcn_mfma_f32_16x16x32_bf16(ax0, b3[0][nt], accH[nt], 0, 0, 0);
                accH[nt] = __builtin_amdgcn_mfma_f32_16x16x32_bf16(ax1, b3[1][nt], accH[nt], 0, 0, 0);
            }
#pragma unroll
            for (int nt = 0; nt < 2; ++nt) {
                int col = nt * 16 + l15;
#pragma unroll
                for (int r = 0; r < 4; ++r)
                    out[(size_t)(n0 + quad * 4 + r) * 32 + col] = accH[nt][r] + obs[col];
            }
        }
    }
}

__global__ void init_h(const float* __restrict__ nf, unsigned short* __restrict__ hbf) {
    int i = blockIdx.x * 256 + threadIdx.x;
    if (i < NN * 64) hbf[i] = f2bf(nf[i]);
}
__global__ void init_x(const float* __restrict__ xyz, float4* __restrict__ x4) {
    int n = blockIdx.x * 256 + threadIdx.x;
    if (n < NN) {
        float4 v;
        v.x = xyz[n * 3 + 0]; v.y = xyz[n * 3 + 1]; v.z = xyz[n * 3 + 2]; v.w = 0.f;
        x4[n] = v;
    }
}

extern "C" void kernel_launch(void* const* d_in, const int* in_sizes, int n_in,
                              void* d_out, int out_size, void* d_ws, size_t ws_size,
                              hipStream_t stream)
{
    const float* node_feat = (const float*)d_in[0];
    const float* xyz   = (const float*)d_in[1];
    const int*   src   = (const int*)d_in[2];
    const int*   dst   = (const int*)d_in[3];
    const float* ew1   = (const float*)d_in[4];
    const float* eb1   = (const float*)d_in[5];
    const float* ew2   = (const float*)d_in[6];
    const float* eb2   = (const float*)d_in[7];
    const float* cw1   = (const float*)d_in[8];
    const float* cb1   = (const float*)d_in[9];
    const float* cw2   = (const float*)d_in[10];
    const float* nw1   = (const float*)d_in[11];
    const float* nb1   = (const float*)d_in[12];
    const float* nw2   = (const float*)d_in[13];
    const float* nb2   = (const float*)d_in[14];
    const float* ln_g  = (const float*)d_in[15];
    const float* ln_b  = (const float*)d_in[16];
    const float* out_w = (const float*)d_in[17];
    const float* out_b = (const float*)d_in[18];
    float* out = (float*)d_out;

    char* ws = (char*)d_ws;
    float* h_neigh = (float*)ws;                 ws += (size_t)NN * 64 * 4;
    unsigned short* hbf = (unsigned short*)ws;   ws += (size_t)NN * 64 * 2;
    float4* xA    = (float4*)ws;                 ws += (size_t)NN * 16;
    float4* xB    = (float4*)ws;                 ws += (size_t)NN * 16;
    float* x_sum  = (float*)ws;                  ws += (size_t)NN * 3 * 4;
    int* rowptr   = (int*)ws;                    ws += (size_t)(NN + 1) * 4;
    int* chunkPtr = (int*)ws;                    ws += (size_t)(NN + 1) * 4;
    int* counts   = (int*)ws;                    ws += (size_t)NN * 4;   // reused as cursor
    int* srcS     = (int*)ws;                    ws += (size_t)NE * 4;
    int2* chunkTbl = (int2*)ws;                  ws += (size_t)(NN + NE / 16) * 8;

    hipMemsetAsync(counts, 0, (size_t)NN * 4, stream);
    init_h<<<(NN * 64 + 255) / 256, 256, 0, stream>>>(node_feat, hbf);
    init_x<<<(NN + 255) / 256, 256, 0, stream>>>(xyz, xA);
    hist_kernel<<<(NE + 255) / 256, 256, 0, stream>>>(dst, counts);
    scan_kernel<<<1, 1024, 0, stream>>>(counts, rowptr, counts, chunkPtr);
    scatter_kernel<<<(NE + 255) / 256, 256, 0, stream>>>(src, dst, counts, srcS);
    fill_chunks<<<(NN + 255) / 256, 256, 0, stream>>>(rowptr, chunkPtr, chunkTbl);

    // layer 0 (computes x for layer 1)
    hipMemsetAsync(h_neigh, 0, (size_t)NN * 64 * 4, stream);
    hipMemsetAsync(x_sum, 0, (size_t)NN * 3 * 4, stream);
    edge3_kernel<true><<<2048, 256, 0, stream>>>(
        xA, hbf, rowptr, srcS, chunkTbl, chunkPtr + NN,
        ew1, eb1, ew2, eb2, cw1, cb1, cw2, h_neigh, x_sum);
    xupd<<<(NN + 255) / 256, 256, 0, stream>>>(x_sum, rowptr, xA, xB);
    node_kernel<false><<<1024, 256, 0, stream>>>(
        hbf, h_neigh, nw1, nb1, nw2, nb2, ln_g, ln_b, out_w, out_b, out);

    // layer 1 (x output dead -> no coord head; head fused into node kernel)
    hipMemsetAsync(h_neigh, 0, (size_t)NN * 64 * 4, stream);
    edge3_kernel<false><<<2048, 256, 0, stream>>>(
        xB, hbf, rowptr, srcS, chunkTbl, chunkPtr + NN,
        ew1 + 129 * 64, eb1 + 64, ew2 + 64 * 64, eb2 + 64,
        cw1 + 64 * 64, cb1 + 64, cw2 + 64, h_neigh, nullptr);
    node_kernel<true><<<1024, 256, 0, stream>>>(
        hbf, h_neigh, nw1 + 128 * 64, nb1 + 64, nw2 + 64 * 64, nb2 + 64,
        ln_g, ln_b, out_w, out_b, out);
}

// Round 7
// 1269.267 us; speedup vs baseline: 1.8644x; 1.1651x over previous
//
#include <hip/hip_runtime.h>
#include <hip/hip_bf16.h>

#define NN 100000
#define NE 1600000
#define SW 136   // padded stride (shorts) for [64][128] bf16 weight tiles
#define ST 68    // padded stride (shorts) for [16][64] bf16 link tiles

typedef __attribute__((ext_vector_type(8))) short bf16x8;
typedef __attribute__((ext_vector_type(4))) float f32x4;

__device__ __forceinline__ unsigned short f2bf(float f) {
    union { float f; unsigned int u; } v; v.f = f;
    unsigned int u = v.u + 0x7fff + ((v.u >> 16) & 1);
    return (unsigned short)(u >> 16);
}
__device__ __forceinline__ unsigned int f2bf2u(float a, float b) {
    union { __hip_bfloat162 h; unsigned int u; } cv;
    cv.h = __float22bfloat162_rn(make_float2(a, b));
    return cv.u;
}
__device__ __forceinline__ float bf2f(unsigned short h) {
    union { unsigned int u; float f; } v; v.u = ((unsigned int)h) << 16;
    return v.f;
}
__device__ __forceinline__ float silu_f(float v) {
    return v / (1.0f + __expf(-v));
}

// ---------------- CSR + chunk-table build ----------------
__global__ void hist_kernel(const int* __restrict__ dst, int* __restrict__ counts) {
    int i = blockIdx.x * 256 + threadIdx.x;
    if (i < NE) atomicAdd(&counts[dst[i]], 1);
}

__global__ __launch_bounds__(1024) void scan_kernel(const int* __restrict__ counts,
                                                    int* __restrict__ rowptr,
                                                    int* __restrict__ cursor,
                                                    int* __restrict__ chunkPtr) {
    __shared__ int tsum[1024], csum[1024];
    const int T = 1024;
    int tid = threadIdx.x;
    const int per = (NN + T - 1) / T;
    int base = tid * per;
    int s = 0, c = 0;
    for (int i = 0; i < per; ++i) {
        int idx = base + i;
        if (idx < NN) { int v = counts[idx]; s += v; c += (v + 15) >> 4; }
    }
    tsum[tid] = s; csum[tid] = c;
    __syncthreads();
    for (int off = 1; off < T; off <<= 1) {
        int v = tsum[tid], w = csum[tid];
        int av = (tid >= off) ? tsum[tid - off] : 0;
        int aw = (tid >= off) ? csum[tid - off] : 0;
        __syncthreads();
        tsum[tid] = v + av; csum[tid] = w + aw;
        __syncthreads();
    }
    int run  = (tid == 0) ? 0 : tsum[tid - 1];
    int crun = (tid == 0) ? 0 : csum[tid - 1];
    for (int i = 0; i < per; ++i) {
        int idx = base + i;
        if (idx < NN) {
            int v = counts[idx];
            rowptr[idx] = run; cursor[idx] = run; chunkPtr[idx] = crun;
            run += v; crun += (v + 15) >> 4;
        }
    }
    if (tid == T - 1) { rowptr[NN] = run; chunkPtr[NN] = crun; }
}

__global__ void scatter_kernel(const int* __restrict__ src, const int* __restrict__ dst,
                               int* __restrict__ cursor, int* __restrict__ srcS) {
    int i = blockIdx.x * 256 + threadIdx.x;
    if (i < NE) {
        int pos = atomicAdd(&cursor[dst[i]], 1);
        srcS[pos] = src[i];
    }
}

__global__ void fill_chunks(const int* __restrict__ rowptr, const int* __restrict__ chunkPtr,
                            int2* __restrict__ chunkTbl) {
    int n = blockIdx.x * 256 + threadIdx.x;
    if (n < NN) {
        int s = rowptr[n], e = rowptr[n + 1];
        int b = chunkPtr[n];
        for (int cs = s, i = 0; cs < e; cs += 16, ++i)
            chunkTbl[b + i] = make_int2(n, cs);
    }
}

// ---------------------------------------------------------------------------
// Prep kernel: per node, Ys = h@W1[0:64] (bf16), Yd = h@W1[64:128]+eb1 (fp32).
// Eliminates GEMM1 from the edge kernel (t1 = silu(Ys[src]+Yd[dst]+rad*w1l)).
// ---------------------------------------------------------------------------
__global__ __launch_bounds__(256, 4) void prep_kernel(
    const unsigned short* __restrict__ hbf,
    const float* __restrict__ ew1,   // [129,64]
    const float* __restrict__ eb1,
    unsigned short* __restrict__ Ys, // [N,64] bf16
    float* __restrict__ Yd)          // [N,64] fp32
{
    __shared__ __align__(16) unsigned short w1sT[64 * ST];
    __shared__ __align__(16) unsigned short w1dT[64 * ST];
    __shared__ float eb1s[64];

    const int tid  = threadIdx.x;
    const int wave = tid >> 6;
    const int lane = tid & 63;
    const int quad = lane >> 4;
    const int l15  = lane & 15;

    for (int i = tid; i < 64 * 64; i += 256) {
        int n = i & 63, k = i >> 6;
        w1sT[n * ST + k] = f2bf(ew1[k * 64 + n]);
        w1dT[n * ST + k] = f2bf(ew1[(64 + k) * 64 + n]);
    }
    if (tid < 64) eb1s[tid] = eb1[tid];
    __syncthreads();

    for (int t = blockIdx.x * 4 + wave; t < NN / 16; t += gridDim.x * 4) {
        const int n0 = t * 16;
        const unsigned short* ph = hbf + (size_t)(n0 + l15) * 64 + quad * 8;
        bf16x8 a0 = *(const bf16x8*)(ph);
        bf16x8 a1 = *(const bf16x8*)(ph + 32);

        f32x4 accS[4], accD[4];
#pragma unroll
        for (int nt = 0; nt < 4; ++nt) {
            accS[nt] = (f32x4){0.f, 0.f, 0.f, 0.f};
            accD[nt] = (f32x4){0.f, 0.f, 0.f, 0.f};
        }
        const unsigned short* bS = &w1sT[l15 * ST + quad * 8];
        const unsigned short* bD = &w1dT[l15 * ST + quad * 8];
#pragma unroll
        for (int nt = 0; nt < 4; ++nt) {
            const unsigned short* bbS = bS + nt * 16 * ST;
            const unsigned short* bbD = bD + nt * 16 * ST;
            accS[nt] = __builtin_amdgcn_mfma_f32_16x16x32_bf16(a0, *(const bf16x8*)(bbS), accS[nt], 0, 0, 0);
            accS[nt] = __builtin_amdgcn_mfma_f32_16x16x32_bf16(a1, *(const bf16x8*)(bbS + 32), accS[nt], 0, 0, 0);
            accD[nt] = __builtin_amdgcn_mfma_f32_16x16x32_bf16(a0, *(const bf16x8*)(bbD), accD[nt], 0, 0, 0);
            accD[nt] = __builtin_amdgcn_mfma_f32_16x16x32_bf16(a1, *(const bf16x8*)(bbD + 32), accD[nt], 0, 0, 0);
        }
#pragma unroll
        for (int nt = 0; nt < 4; ++nt) {
            int col = nt * 16 + l15;
#pragma unroll
            for (int r = 0; r < 4; ++r) {
                int n = n0 + quad * 4 + r;
                Ys[(size_t)n * 64 + col] = f2bf(accS[nt][r]);
                Yd[(size_t)n * 64 + col] = accD[nt][r] + eb1s[col];
            }
        }
    }
}

// ---------------------------------------------------------------------------
// Edge kernel (chunk-parallel, stateless body): t1 built in A-layout registers
// directly from gathered Ys[src] + broadcast Yd[dst] + rad*w1l -> silu.
// Then GEMM2 (msg), chunk-reduced atomics; layer0 adds GEMM3 coord head.
// ---------------------------------------------------------------------------
template <bool WRITE_X>
__global__ __launch_bounds__(256, 3) void edge4_kernel(
    const float4* __restrict__ x4,
    const unsigned short* __restrict__ Ys,
    const float* __restrict__ Yd,
    const int* __restrict__ rowptr,
    const int* __restrict__ srcS,
    const int2* __restrict__ chunkTbl,
    const int* __restrict__ chunkCnt,
    const float* __restrict__ ew1,   // for w1l = row 128
    const float* __restrict__ ew2,   // [64,64]
    const float* __restrict__ eb2,
    const float* __restrict__ cw1,   // [64,64]
    const float* __restrict__ cb1,
    const float* __restrict__ cw2,   // [64]
    float* __restrict__ h_neigh,     // [N,64] fp32 (pre-zeroed)
    float* __restrict__ x_sum)       // [N,3] fp32 (pre-zeroed, WRITE_X only)
{
    __shared__ __align__(16) unsigned short w2T[64 * ST];      // B^T GEMM2
    __shared__ __align__(16) unsigned short c1T[64 * ST];      // B^T GEMM3
    __shared__ __align__(16) unsigned short tAll[4 * 16 * ST]; // per-wave link buf
    __shared__ __align__(16) float w1ls[64];
    __shared__ float eb2s[64], cb1s[64], cw2s[64];

    const int tid  = threadIdx.x;
    const int wave = tid >> 6;
    const int lane = tid & 63;
    const int quad = lane >> 4;
    const int l15  = lane & 15;

    for (int i = tid; i < 64 * 64; i += 256) {
        int n = i & 63, k = i >> 6;
        w2T[n * ST + k] = f2bf(ew2[k * 64 + n]);
    }
    if (WRITE_X) {
        for (int i = tid; i < 64 * 64; i += 256) {
            int n = i & 63, k = i >> 6;
            c1T[n * ST + k] = f2bf(cw1[k * 64 + n]);
        }
    }
    if (tid < 64) {
        eb2s[tid] = eb2[tid]; cb1s[tid] = cb1[tid];
        cw2s[tid] = cw2[tid]; w1ls[tid] = ew1[128 * 64 + tid];
    }
    __syncthreads();   // only barrier

    unsigned short* tW = tAll + wave * 16 * ST;
    const int C  = chunkCnt[0];
    const int gw = blockIdx.x * 4 + wave;
    const int nw = gridDim.x * 4;

    // loop-invariant w1l slice for this lane's k-columns
    float4 wl0 = *(const float4*)&w1ls[quad * 8];
    float4 wl1 = *(const float4*)&w1ls[quad * 8 + 4];
    float4 wl2 = *(const float4*)&w1ls[32 + quad * 8];
    float4 wl3 = *(const float4*)&w1ls[32 + quad * 8 + 4];

    for (int idx = gw; idx < C; idx += nw) {
        const int2 ck = chunkTbl[idx];
        const int n = ck.x, cs = ck.y;
        const int segE = rowptr[n + 1];

        // lanes 0..15: edge metadata
        int s = n; float rad = 0.f, xdx = 0.f, xdy = 0.f, xdz = 0.f;
        if (lane < 16) {
            int e = cs + lane;
            if (e < segE) {
                s = srcS[e];
                float4 xs = x4[s];
                float4 xn = x4[n];
                float dx = xs.x - xn.x;
                float dy = xs.y - xn.y;
                float dz = xs.z - xn.z;
                rad = dx * dx + dy * dy + dz * dz;
                float inv = 1.0f / (sqrtf(rad) + 1e-30f);
                xdx = dx * inv; xdy = dy * inv; xdz = dz * inv;
            }
        }
        const int rowS = __shfl(s, l15);
        const float radL = __shfl(rad, l15);   // this lane's A-row edge radial

        float radR[4]; float cxR[4], cyR[4], czR[4]; bool valR[4];
#pragma unroll
        for (int r = 0; r < 4; ++r) {
            int er = quad * 4 + r;
            radR[r] = __shfl(rad, er);
            valR[r] = (cs + er) < segE;
            if (WRITE_X) {
                cxR[r] = __shfl(xdx, er);
                cyR[r] = __shfl(xdy, er);
                czR[r] = __shfl(xdz, er);
            }
        }
        (void)radR;

        // ---- build t1 A-frags in registers: silu(Ys[src] + Yd[n] + radL*w1l)
        const unsigned short* ps = Ys + (size_t)rowS * 64 + quad * 8;
        bf16x8 g0 = *(const bf16x8*)(ps);
        bf16x8 g1 = *(const bf16x8*)(ps + 32);
        const float* pyd = Yd + (size_t)n * 64 + quad * 8;
        float4 y0 = *(const float4*)(pyd);
        float4 y1 = *(const float4*)(pyd + 4);
        float4 y2 = *(const float4*)(pyd + 32);
        float4 y3 = *(const float4*)(pyd + 36);

        bf16x8 aF0, aF1;
        {
            const unsigned short* pg0 = (const unsigned short*)&g0;
            const unsigned short* pg1 = (const unsigned short*)&g1;
            float t0[8], t1v[8];
            const float* py0 = (const float*)&y0;
            const float* py1 = (const float*)&y1;
            const float* pw0 = (const float*)&wl0;
            const float* pw1 = (const float*)&wl1;
            const float* py2 = (const float*)&y2;
            const float* py3 = (const float*)&y3;
            const float* pw2 = (const float*)&wl2;
            const float* pw3 = (const float*)&wl3;
#pragma unroll
            for (int j = 0; j < 4; ++j) {
                t0[j]     = silu_f(bf2f(pg0[j])     + py0[j] + radL * pw0[j]);
                t0[j + 4] = silu_f(bf2f(pg0[j + 4]) + py1[j] + radL * pw1[j]);
                t1v[j]     = silu_f(bf2f(pg1[j])     + py2[j] + radL * pw2[j]);
                t1v[j + 4] = silu_f(bf2f(pg1[j + 4]) + py3[j] + radL * pw3[j]);
            }
            unsigned int* pa0 = (unsigned int*)&aF0;
            unsigned int* pa1 = (unsigned int*)&aF1;
#pragma unroll
            for (int j = 0; j < 4; ++j) {
                pa0[j] = f2bf2u(t0[j * 2], t0[j * 2 + 1]);
                pa1[j] = f2bf2u(t1v[j * 2], t1v[j * 2 + 1]);
            }
        }

        // ---- GEMM2: K=64 (B from LDS)
        f32x4 acc2[4];
#pragma unroll
        for (int nt = 0; nt < 4; ++nt) acc2[nt] = (f32x4){0.f, 0.f, 0.f, 0.f};
        {
            const unsigned short* bBase = &w2T[l15 * ST + quad * 8];
#pragma unroll
            for (int nt = 0; nt < 4; ++nt) {
                const unsigned short* bb = bBase + nt * 16 * ST;
                acc2[nt] = __builtin_amdgcn_mfma_f32_16x16x32_bf16(aF0, *(const bf16x8*)(bb), acc2[nt], 0, 0, 0);
                acc2[nt] = __builtin_amdgcn_mfma_f32_16x16x32_bf16(aF1, *(const bf16x8*)(bb + 32), acc2[nt], 0, 0, 0);
            }
        }
        // epilogue2: silu -> msg; per-chunk column reduce -> atomics; tW for GEMM3
#pragma unroll
        for (int nt = 0; nt < 4; ++nt) {
            int col = nt * 16 + l15;
            float colsum = 0.f;
#pragma unroll
            for (int r = 0; r < 4; ++r) {
                float v = silu_f(acc2[nt][r] + eb2s[col]);
                if (valR[r]) colsum += v;
                if (WRITE_X) tW[(quad * 4 + r) * ST + col] = f2bf(v);
            }
            colsum += __shfl_xor(colsum, 16);
            colsum += __shfl_xor(colsum, 32);
            if (quad == 0) atomicAdd(&h_neigh[(size_t)n * 64 + col], colsum);
        }
        if (WRITE_X) {
            // GEMM3: K=64
            f32x4 acc3[4];
#pragma unroll
            for (int nt = 0; nt < 4; ++nt) acc3[nt] = (f32x4){0.f, 0.f, 0.f, 0.f};
            {
                bf16x8 ax0 = *(const bf16x8*)&tW[l15 * ST + quad * 8];
                bf16x8 ax1 = *(const bf16x8*)&tW[l15 * ST + 32 + quad * 8];
                const unsigned short* bBase = &c1T[l15 * ST + quad * 8];
#pragma unroll
                for (int nt = 0; nt < 4; ++nt) {
                    const unsigned short* bb = bBase + nt * 16 * ST;
                    acc3[nt] = __builtin_amdgcn_mfma_f32_16x16x32_bf16(ax0, *(const bf16x8*)(bb), acc3[nt], 0, 0, 0);
                    acc3[nt] = __builtin_amdgcn_mfma_f32_16x16x32_bf16(ax1, *(const bf16x8*)(bb + 32), acc3[nt], 0, 0, 0);
                }
            }
            float part_[4] = {0.f, 0.f, 0.f, 0.f};
#pragma unroll
            for (int nt = 0; nt < 4; ++nt) {
                int col = nt * 16 + l15;
#pragma unroll
                for (int r = 0; r < 4; ++r)
                    part_[r] += silu_f(acc3[nt][r] + cb1s[col]) * cw2s[col];
            }
            float xc = 0.f;
#pragma unroll
            for (int r = 0; r < 4; ++r) {
                float p = part_[r];
                p += __shfl_xor(p, 1);
                p += __shfl_xor(p, 2);
                p += __shfl_xor(p, 4);
                p += __shfl_xor(p, 8);
                if (valR[r]) {
                    float comp = (l15 == 0) ? cxR[r] : (l15 == 1) ? cyR[r] : czR[r];
                    xc += p * comp;
                }
            }
            xc += __shfl_xor(xc, 16);
            xc += __shfl_xor(xc, 32);
            if (quad == 0 && l15 < 3)
                atomicAdd(&x_sum[(size_t)n * 3 + l15], xc);
        }
    }
}

__global__ void xupd(const float* __restrict__ x_sum, const int* __restrict__ rowptr,
                     const float4* __restrict__ xin, float4* __restrict__ xout) {
    int n = blockIdx.x * 256 + threadIdx.x;
    if (n < NN) {
        float d = (float)(rowptr[n + 1] - rowptr[n]);
        float id = 1.0f / fmaxf(d, 1.0f);
        float4 v = xin[n];
        v.x += x_sum[n * 3 + 0] * id;
        v.y += x_sum[n * 3 + 1] * id;
        v.z += x_sum[n * 3 + 2] * id;
        v.w = 0.f;
        xout[n] = v;
    }
}

// ---------------------------------------------------------------------------
// Node kernel: h_new = silu([h|h_neigh]@NW1+nb1)@NW2+nb2 -> gelu -> LayerNorm.
// ---------------------------------------------------------------------------
template <bool DO_HEAD>
__global__ __launch_bounds__(256, 4) void node_kernel(
    unsigned short* hbf,
    const float* __restrict__ h_nb,   // [N,64] fp32
    const float* __restrict__ nw1,
    const float* __restrict__ nb1,
    const float* __restrict__ nw2,
    const float* __restrict__ nb2,
    const float* __restrict__ ln_g,
    const float* __restrict__ ln_b,
    const float* __restrict__ out_w,  // [64,32]
    const float* __restrict__ out_b,  // [32]
    float* __restrict__ out)          // [N,32]
{
    __shared__ __align__(16) unsigned short w1T[64 * SW];
    __shared__ __align__(16) unsigned short w2T[64 * ST];
    __shared__ __align__(16) unsigned short tAll[4 * 16 * ST];
    __shared__ float nb1s[64], nb2s[64], gs[64], bs[64], obs[32];

    const int tid  = threadIdx.x;
    const int wave = tid >> 6;
    const int lane = tid & 63;
    const int quad = lane >> 4;
    const int l15  = lane & 15;

    for (int i = tid; i < 64 * 128; i += 256) {
        int n = i & 63, k = i >> 6;
        w1T[n * SW + k] = f2bf(nw1[k * 64 + n]);
    }
    for (int i = tid; i < 64 * 64; i += 256) {
        int n = i & 63, k = i >> 6;
        w2T[n * ST + k] = f2bf(nw2[k * 64 + n]);
    }
    if (tid < 64) {
        nb1s[tid] = nb1[tid]; nb2s[tid] = nb2[tid];
        gs[tid] = ln_g[tid]; bs[tid] = ln_b[tid];
        if (DO_HEAD && tid < 32) obs[tid] = out_b[tid];
    }
    bf16x8 b3[2][2];
    if (DO_HEAD) {
#pragma unroll
        for (int ks = 0; ks < 2; ++ks)
#pragma unroll
            for (int nt = 0; nt < 2; ++nt) {
#pragma unroll
                for (int j = 0; j < 8; ++j) {
                    int k = ks * 32 + quad * 8 + j;
                    ((unsigned short*)&b3[ks][nt])[j] = f2bf(out_w[k * 32 + nt * 16 + l15]);
                }
            }
    }
    __syncthreads();

    unsigned short* tW = tAll + wave * 16 * ST;

    for (int t = blockIdx.x * 4 + wave; t < NN / 16; t += gridDim.x * 4) {
        const int n0 = t * 16;
        const int myRow = n0 + l15;
        const unsigned short* ph = hbf + (size_t)myRow * 64 + quad * 8;
        bf16x8 a0 = *(const bf16x8*)(ph);
        bf16x8 a1 = *(const bf16x8*)(ph + 32);
        bf16x8 a2, a3;
        {
            const float* pb = h_nb + (size_t)myRow * 64 + quad * 8;
            float4 v0 = *(const float4*)(pb);
            float4 v1 = *(const float4*)(pb + 4);
            float4 v2 = *(const float4*)(pb + 32);
            float4 v3 = *(const float4*)(pb + 36);
            unsigned int* pa2 = (unsigned int*)&a2;
            unsigned int* pa3 = (unsigned int*)&a3;
            pa2[0] = f2bf2u(v0.x, v0.y); pa2[1] = f2bf2u(v0.z, v0.w);
            pa2[2] = f2bf2u(v1.x, v1.y); pa2[3] = f2bf2u(v1.z, v1.w);
            pa3[0] = f2bf2u(v2.x, v2.y); pa3[1] = f2bf2u(v2.z, v2.w);
            pa3[2] = f2bf2u(v3.x, v3.y); pa3[3] = f2bf2u(v3.z, v3.w);
        }

        f32x4 acc[4];
#pragma unroll
        for (int nt = 0; nt < 4; ++nt) acc[nt] = (f32x4){0.f, 0.f, 0.f, 0.f};
        {
            const unsigned short* bBase = &w1T[l15 * SW + quad * 8];
#pragma unroll
            for (int nt = 0; nt < 4; ++nt) {
                const unsigned short* bb = bBase + nt * 16 * SW;
                acc[nt] = __builtin_amdgcn_mfma_f32_16x16x32_bf16(a0, *(const bf16x8*)(bb), acc[nt], 0, 0, 0);
                acc[nt] = __builtin_amdgcn_mfma_f32_16x16x32_bf16(a1, *(const bf16x8*)(bb + 32), acc[nt], 0, 0, 0);
                acc[nt] = __builtin_amdgcn_mfma_f32_16x16x32_bf16(a2, *(const bf16x8*)(bb + 64), acc[nt], 0, 0, 0);
                acc[nt] = __builtin_amdgcn_mfma_f32_16x16x32_bf16(a3, *(const bf16x8*)(bb + 96), acc[nt], 0, 0, 0);
            }
        }
#pragma unroll
        for (int nt = 0; nt < 4; ++nt) {
            int col = nt * 16 + l15;
#pragma unroll
            for (int r = 0; r < 4; ++r) {
                float v = acc[nt][r] + nb1s[col];
                tW[(quad * 4 + r) * ST + col] = f2bf(silu_f(v));
            }
        }
        f32x4 acc2[4];
#pragma unroll
        for (int nt = 0; nt < 4; ++nt) acc2[nt] = (f32x4){0.f, 0.f, 0.f, 0.f};
        {
            bf16x8 ax0 = *(const bf16x8*)&tW[l15 * ST + quad * 8];
            bf16x8 ax1 = *(const bf16x8*)&tW[l15 * ST + 32 + quad * 8];
            const unsigned short* bBase = &w2T[l15 * ST + quad * 8];
#pragma unroll
            for (int nt = 0; nt < 4; ++nt) {
                const unsigned short* bb = bBase + nt * 16 * ST;
                acc2[nt] = __builtin_amdgcn_mfma_f32_16x16x32_bf16(ax0, *(const bf16x8*)(bb), acc2[nt], 0, 0, 0);
                acc2[nt] = __builtin_amdgcn_mfma_f32_16x16x32_bf16(ax1, *(const bf16x8*)(bb + 32), acc2[nt], 0, 0, 0);
            }
        }
        float vals[4][4];
        float sum[4] = {0.f, 0.f, 0.f, 0.f}, ss[4] = {0.f, 0.f, 0.f, 0.f};
#pragma unroll
        for (int nt = 0; nt < 4; ++nt) {
            int col = nt * 16 + l15;
#pragma unroll
            for (int r = 0; r < 4; ++r) {
                float v = acc2[nt][r] + nb2s[col];
                float g = 0.5f * v * (1.0f + erff(v * 0.70710678118654752f));
                vals[nt][r] = g;
                sum[r] += g;
                ss[r] += g * g;
            }
        }
#pragma unroll
        for (int r = 0; r < 4; ++r) {
            float s1 = sum[r], s2 = ss[r];
            s1 += __shfl_xor(s1, 1); s2 += __shfl_xor(s2, 1);
            s1 += __shfl_xor(s1, 2); s2 += __shfl_xor(s2, 2);
            s1 += __shfl_xor(s1, 4); s2 += __shfl_xor(s2, 4);
            s1 += __shfl_xor(s1, 8); s2 += __shfl_xor(s2, 8);
            sum[r] = s1; ss[r] = s2;
        }
#pragma unroll
        for (int r = 0; r < 4; ++r) {
            float mean = sum[r] * (1.0f / 64.0f);
            float var  = ss[r] * (1.0f / 64.0f) - mean * mean;
            float rstd = rsqrtf(var + 1e-5f);
            int n = n0 + quad * 4 + r;
#pragma unroll
            for (int nt = 0; nt < 4; ++nt) {
                int col = nt * 16 + l15;
                float y = (vals[nt][r] - mean) * rstd * gs[col] + bs[col];
                if (DO_HEAD) tW[(quad * 4 + r) * ST + col] = f2bf(y);
                else hbf[(size_t)n * 64 + col] = f2bf(y);
            }
        }
        if (DO_HEAD) {
            f32x4 accH[2];
#pragma unroll
            for (int nt = 0; nt < 2; ++nt) accH[nt] = (f32x4){0.f, 0.f, 0.f, 0.f};
            bf16x8 ax0 = *(const bf16x8*)&tW[l15 * ST + quad * 8];
            bf16x8 ax1 = *(const bf16x8*)&tW[l15 * ST + 32 + quad * 8];
#pragma unroll
            for (int nt = 0; nt < 2; ++nt) {
                accH[nt] = __builtin_amdgcn_mfma_f32_16x16x32_bf16(ax0, b3[0][nt], accH[nt], 0, 0, 0);
                accH[nt] = __builtin_amdgcn_mfma_f32_16x16x32_bf16(ax1, b3[1][nt], accH[nt], 0, 0, 0);
            }
#pragma unroll
            for (int nt = 0; nt < 2; ++nt) {
                int col = nt * 16 + l15;
#pragma unroll
                for (int r = 0; r < 4; ++r)
                    out[(size_t)(n0 + quad * 4 + r) * 32 + col] = accH[nt][r] + obs[col];
            }
        }
    }
}

__global__ void init_h(const float* __restrict__ nf, unsigned short* __restrict__ hbf) {
    int i = blockIdx.x * 256 + threadIdx.x;
    if (i < NN * 64) hbf[i] = f2bf(nf[i]);
}
__global__ void init_x(const float* __restrict__ xyz, float4* __restrict__ x4) {
    int n = blockIdx.x * 256 + threadIdx.x;
    if (n < NN) {
        float4 v;
        v.x = xyz[n * 3 + 0]; v.y = xyz[n * 3 + 1]; v.z = xyz[n * 3 + 2]; v.w = 0.f;
        x4[n] = v;
    }
}

extern "C" void kernel_launch(void* const* d_in, const int* in_sizes, int n_in,
                              void* d_out, int out_size, void* d_ws, size_t ws_size,
                              hipStream_t stream)
{
    const float* node_feat = (const float*)d_in[0];
    const float* xyz   = (const float*)d_in[1];
    const int*   src   = (const int*)d_in[2];
    const int*   dst   = (const int*)d_in[3];
    const float* ew1   = (const float*)d_in[4];
    const float* eb1   = (const float*)d_in[5];
    const float* ew2   = (const float*)d_in[6];
    const float* eb2   = (const float*)d_in[7];
    const float* cw1   = (const float*)d_in[8];
    const float* cb1   = (const float*)d_in[9];
    const float* cw2   = (const float*)d_in[10];
    const float* nw1   = (const float*)d_in[11];
    const float* nb1   = (const float*)d_in[12];
    const float* nw2   = (const float*)d_in[13];
    const float* nb2   = (const float*)d_in[14];
    const float* ln_g  = (const float*)d_in[15];
    const float* ln_b  = (const float*)d_in[16];
    const float* out_w = (const float*)d_in[17];
    const float* out_b = (const float*)d_in[18];
    float* out = (float*)d_out;

    char* ws = (char*)d_ws;
    float* h_neigh = (float*)ws;                 ws += (size_t)NN * 64 * 4;
    unsigned short* hbf = (unsigned short*)ws;   ws += (size_t)NN * 64 * 2;
    unsigned short* Ys  = (unsigned short*)ws;   ws += (size_t)NN * 64 * 2;
    float* Yd     = (float*)ws;                  ws += (size_t)NN * 64 * 4;
    float4* xA    = (float4*)ws;                 ws += (size_t)NN * 16;
    float4* xB    = (float4*)ws;                 ws += (size_t)NN * 16;
    float* x_sum  = (float*)ws;                  ws += (size_t)NN * 3 * 4;
    int* rowptr   = (int*)ws;                    ws += (size_t)(NN + 1) * 4;
    int* chunkPtr = (int*)ws;                    ws += (size_t)(NN + 1) * 4;
    int* counts   = (int*)ws;                    ws += (size_t)NN * 4;   // reused as cursor
    int* srcS     = (int*)ws;                    ws += (size_t)NE * 4;
    int2* chunkTbl = (int2*)ws;                  ws += (size_t)(NN + NE / 16) * 8;

    hipMemsetAsync(counts, 0, (size_t)NN * 4, stream);
    init_h<<<(NN * 64 + 255) / 256, 256, 0, stream>>>(node_feat, hbf);
    init_x<<<(NN + 255) / 256, 256, 0, stream>>>(xyz, xA);
    hist_kernel<<<(NE + 255) / 256, 256, 0, stream>>>(dst, counts);
    scan_kernel<<<1, 1024, 0, stream>>>(counts, rowptr, counts, chunkPtr);
    scatter_kernel<<<(NE + 255) / 256, 256, 0, stream>>>(src, dst, counts, srcS);
    fill_chunks<<<(NN + 255) / 256, 256, 0, stream>>>(rowptr, chunkPtr, chunkTbl);

    // ---- layer 0 (computes x for layer 1)
    hipMemsetAsync(h_neigh, 0, (size_t)NN * 64 * 4, stream);
    hipMemsetAsync(x_sum, 0, (size_t)NN * 3 * 4, stream);
    prep_kernel<<<1024, 256, 0, stream>>>(hbf, ew1, eb1, Ys, Yd);
    edge4_kernel<true><<<2048, 256, 0, stream>>>(
        xA, Ys, Yd, rowptr, srcS, chunkTbl, chunkPtr + NN,
        ew1, ew2, eb2, cw1, cb1, cw2, h_neigh, x_sum);
    xupd<<<(NN + 255) / 256, 256, 0, stream>>>(x_sum, rowptr, xA, xB);
    node_kernel<false><<<1024, 256, 0, stream>>>(
        hbf, h_neigh, nw1, nb1, nw2, nb2, ln_g, ln_b, out_w, out_b, out);

    // ---- layer 1 (x output dead -> no coord head; head fused into node kernel)
    hipMemsetAsync(h_neigh, 0, (size_t)NN * 64 * 4, stream);
    prep_kernel<<<1024, 256, 0, stream>>>(hbf, ew1 + 129 * 64, eb1 + 64, Ys, Yd);
    edge4_kernel<false><<<2048, 256, 0, stream>>>(
        xB, Ys, Yd, rowptr, srcS, chunkTbl, chunkPtr + NN,
        ew1 + 129 * 64, ew2 + 64 * 64, eb2 + 64, cw1 + 64 * 64, cb1 + 64, cw2 + 64,
        h_neigh, nullptr);
    node_kernel<true><<<1024, 256, 0, stream>>>(
        hbf, h_neigh, nw1 + 128 * 64, nb1 + 64, nw2 + 64 * 64, nb2 + 64,
        ln_g, ln_b, out_w, out_b, out);
}

// Round 8
// 958.724 us; speedup vs baseline: 2.4683x; 1.3239x over previous
//
#include <hip/hip_runtime.h>
#include <hip/hip_bf16.h>

#define NN 100000
#define NE 1600000
#define SW 136   // padded stride (shorts) for [64][128] bf16 weight tiles
#define ST 68    // padded stride (shorts) for [16][64] bf16 link tiles
#define STF 68   // padded stride (floats) for fp32 link tiles

typedef __attribute__((ext_vector_type(8))) short bf16x8;
typedef __attribute__((ext_vector_type(4))) float f32x4;

__device__ __forceinline__ unsigned short f2bf(float f) {
    union { float f; unsigned int u; } v; v.f = f;
    unsigned int u = v.u + 0x7fff + ((v.u >> 16) & 1);
    return (unsigned short)(u >> 16);
}
__device__ __forceinline__ unsigned int f2bf2u(float a, float b) {
    union { __hip_bfloat162 h; unsigned int u; } cv;
    cv.h = __float22bfloat162_rn(make_float2(a, b));
    return cv.u;
}
__device__ __forceinline__ float bf2f(unsigned short h) {
    union { unsigned int u; float f; } v; v.u = ((unsigned int)h) << 16;
    return v.f;
}
__device__ __forceinline__ float silu_f(float v) {
    return v / (1.0f + __expf(-v));
}

// ---------------- CSR + chunk-table build (parallel scan) ----------------
__global__ void hist_kernel(const int* __restrict__ dst, int* __restrict__ counts) {
    int i = blockIdx.x * 256 + threadIdx.x;
    if (i < NE) atomicAdd(&counts[dst[i]], 1);
}

#define SCAN_BLK ((NN + 1023) / 1024)   // 98 blocks, 1024 nodes each

__global__ __launch_bounds__(256) void scanA(const int* __restrict__ counts,
                                             int2* __restrict__ blockTot) {
    __shared__ int sS[256], sC[256];
    int tid = threadIdx.x;
    int base = blockIdx.x * 1024 + tid * 4;
    int s = 0, c = 0;
#pragma unroll
    for (int j = 0; j < 4; ++j) {
        int idx = base + j;
        if (idx < NN) { int v = counts[idx]; s += v; c += (v + 15) >> 4; }
    }
    sS[tid] = s; sC[tid] = c;
    __syncthreads();
    for (int off = 128; off > 0; off >>= 1) {
        if (tid < off) { sS[tid] += sS[tid + off]; sC[tid] += sC[tid + off]; }
        __syncthreads();
    }
    if (tid == 0) blockTot[blockIdx.x] = make_int2(sS[0], sC[0]);
}

__global__ __launch_bounds__(128) void scanB(int2* __restrict__ blockTot,
                                             int* __restrict__ rowptr,
                                             int* __restrict__ chunkPtr) {
    __shared__ int sS[128], sC[128];
    int tid = threadIdx.x;
    int2 v = (tid < SCAN_BLK) ? blockTot[tid] : make_int2(0, 0);
    sS[tid] = v.x; sC[tid] = v.y;
    __syncthreads();
    for (int off = 1; off < 128; off <<= 1) {
        int aS = sS[tid], aC = sC[tid];
        int bS = (tid >= off) ? sS[tid - off] : 0;
        int bC = (tid >= off) ? sC[tid - off] : 0;
        __syncthreads();
        sS[tid] = aS + bS; sC[tid] = aC + bC;
        __syncthreads();
    }
    if (tid < SCAN_BLK) blockTot[tid] = make_int2(sS[tid] - v.x, sC[tid] - v.y); // exclusive
    if (tid == 127) { rowptr[NN] = sS[127]; chunkPtr[NN] = sC[127]; }
}

__global__ __launch_bounds__(256) void scanC(const int* __restrict__ counts,
                                             const int2* __restrict__ blockTot,
                                             int* __restrict__ rowptr,
                                             int* __restrict__ cursor,
                                             int* __restrict__ chunkPtr) {
    __shared__ int sS[256], sC[256];
    int tid = threadIdx.x;
    int base = blockIdx.x * 1024 + tid * 4;
    int vloc[4]; int s = 0, c = 0;
#pragma unroll
    for (int j = 0; j < 4; ++j) {
        int idx = base + j;
        vloc[j] = (idx < NN) ? counts[idx] : 0;
        s += vloc[j]; c += (vloc[j] + 15) >> 4;
    }
    sS[tid] = s; sC[tid] = c;
    __syncthreads();
    for (int off = 1; off < 256; off <<= 1) {
        int aS = sS[tid], aC = sC[tid];
        int bS = (tid >= off) ? sS[tid - off] : 0;
        int bC = (tid >= off) ? sC[tid - off] : 0;
        __syncthreads();
        sS[tid] = aS + bS; sC[tid] = aC + bC;
        __syncthreads();
    }
    int2 bo = blockTot[blockIdx.x];
    int runS = bo.x + sS[tid] - s;
    int runC = bo.y + sC[tid] - c;
#pragma unroll
    for (int j = 0; j < 4; ++j) {
        int idx = base + j;
        if (idx < NN) {
            rowptr[idx] = runS; cursor[idx] = runS; chunkPtr[idx] = runC;
            runS += vloc[j]; runC += (vloc[j] + 15) >> 4;
        }
    }
}

__global__ void scatter_kernel(const int* __restrict__ src, const int* __restrict__ dst,
                               int* __restrict__ cursor, int* __restrict__ srcS) {
    int i = blockIdx.x * 256 + threadIdx.x;
    if (i < NE) {
        int pos = atomicAdd(&cursor[dst[i]], 1);
        srcS[pos] = src[i];
    }
}

// chunkTbl entry: (n, cs | len<<25), len in [1,16]
__global__ void fill_chunks(const int* __restrict__ rowptr, const int* __restrict__ chunkPtr,
                            int2* __restrict__ chunkTbl) {
    int n = blockIdx.x * 256 + threadIdx.x;
    if (n < NN) {
        int s = rowptr[n], e = rowptr[n + 1];
        int b = chunkPtr[n];
        for (int cs = s, i = 0; cs < e; cs += 16, ++i) {
            int len = min(16, e - cs);
            chunkTbl[b + i] = make_int2(n, cs | (len << 25));
        }
    }
}

// ---------------------------------------------------------------------------
// Prep kernel: per node, Ys = h@W1[0:64] (bf16), Yd = h@W1[64:128]+eb1 (fp32).
// ---------------------------------------------------------------------------
__global__ __launch_bounds__(256, 4) void prep_kernel(
    const unsigned short* __restrict__ hbf,
    const float* __restrict__ ew1,   // [129,64]
    const float* __restrict__ eb1,
    unsigned short* __restrict__ Ys, // [N,64] bf16
    float* __restrict__ Yd)          // [N,64] fp32
{
    __shared__ __align__(16) unsigned short w1sT[64 * ST];
    __shared__ __align__(16) unsigned short w1dT[64 * ST];
    __shared__ float eb1s[64];

    const int tid  = threadIdx.x;
    const int wave = tid >> 6;
    const int lane = tid & 63;
    const int quad = lane >> 4;
    const int l15  = lane & 15;

    for (int i = tid; i < 64 * 64; i += 256) {
        int n = i & 63, k = i >> 6;
        w1sT[n * ST + k] = f2bf(ew1[k * 64 + n]);
        w1dT[n * ST + k] = f2bf(ew1[(64 + k) * 64 + n]);
    }
    if (tid < 64) eb1s[tid] = eb1[tid];
    __syncthreads();

    for (int t = blockIdx.x * 4 + wave; t < NN / 16; t += gridDim.x * 4) {
        const int n0 = t * 16;
        const unsigned short* ph = hbf + (size_t)(n0 + l15) * 64 + quad * 8;
        bf16x8 a0 = *(const bf16x8*)(ph);
        bf16x8 a1 = *(const bf16x8*)(ph + 32);

        f32x4 accS[4], accD[4];
#pragma unroll
        for (int nt = 0; nt < 4; ++nt) {
            accS[nt] = (f32x4){0.f, 0.f, 0.f, 0.f};
            accD[nt] = (f32x4){0.f, 0.f, 0.f, 0.f};
        }
        const unsigned short* bS = &w1sT[l15 * ST + quad * 8];
        const unsigned short* bD = &w1dT[l15 * ST + quad * 8];
#pragma unroll
        for (int nt = 0; nt < 4; ++nt) {
            const unsigned short* bbS = bS + nt * 16 * ST;
            const unsigned short* bbD = bD + nt * 16 * ST;
            accS[nt] = __builtin_amdgcn_mfma_f32_16x16x32_bf16(a0, *(const bf16x8*)(bbS), accS[nt], 0, 0, 0);
            accS[nt] = __builtin_amdgcn_mfma_f32_16x16x32_bf16(a1, *(const bf16x8*)(bbS + 32), accS[nt], 0, 0, 0);
            accD[nt] = __builtin_amdgcn_mfma_f32_16x16x32_bf16(a0, *(const bf16x8*)(bbD), accD[nt], 0, 0, 0);
            accD[nt] = __builtin_amdgcn_mfma_f32_16x16x32_bf16(a1, *(const bf16x8*)(bbD + 32), accD[nt], 0, 0, 0);
        }
#pragma unroll
        for (int nt = 0; nt < 4; ++nt) {
            int col = nt * 16 + l15;
#pragma unroll
            for (int r = 0; r < 4; ++r) {
                int n = n0 + quad * 4 + r;
                Ys[(size_t)n * 64 + col] = f2bf(accS[nt][r]);
                Yd[(size_t)n * 64 + col] = accD[nt][r] + eb1s[col];
            }
        }
    }
}

// ---------------------------------------------------------------------------
// Edge kernel v5 (chunk-parallel, stateless body):
//  - B-frags (W2, CW1) in REGISTERS loaded once from global (loop-invariant);
//  - t1 built in A-layout registers from Ys[src]/Yd[dst]/rad;
//  - fp32 link buffer for GEMM3 (v_cvt_pk on read; no scalar f2bf);
//  - chunkTbl packs len (no rowptr read);
//  - template-sized LDS + per-template launch bounds (layer1: ~1KB LDS).
// ---------------------------------------------------------------------------
template <bool WRITE_X, int MINW>
__global__ __launch_bounds__(256, MINW) void edge5_kernel(
    const float4* __restrict__ x4,
    const unsigned short* __restrict__ Ys,
    const float* __restrict__ Yd,
    const int* __restrict__ srcS,
    const int2* __restrict__ chunkTbl,
    const int* __restrict__ chunkCnt,
    const float* __restrict__ ew1,   // for w1l = row 128
    const float* __restrict__ ew2,   // [64,64]
    const float* __restrict__ eb2,
    const float* __restrict__ cw1,   // [64,64]
    const float* __restrict__ cb1,
    const float* __restrict__ cw2,   // [64]
    float* __restrict__ h_neigh,     // [N,64] fp32 (pre-zeroed)
    float* __restrict__ x_sum)       // [N,3] fp32 (pre-zeroed, WRITE_X only)
{
    constexpr int TWN = WRITE_X ? (4 * 16 * STF) : 4;
    __shared__ __align__(16) float tWF[TWN];       // per-wave fp32 link buf (layer0)
    __shared__ __align__(16) float w1ls[64];
    __shared__ float eb2s[64], cb1s[64], cw2s[64];

    const int tid  = threadIdx.x;
    const int wave = tid >> 6;
    const int lane = tid & 63;
    const int quad = lane >> 4;
    const int l15  = lane & 15;

    if (tid < 64) {
        eb2s[tid] = eb2[tid]; cb1s[tid] = cb1[tid];
        cw2s[tid] = cw2[tid]; w1ls[tid] = ew1[128 * 64 + tid];
    }
    // B-frags from global, once per block (loop-invariant registers)
    bf16x8 b2[2][4], b3[2][4];
#pragma unroll
    for (int ks = 0; ks < 2; ++ks)
#pragma unroll
        for (int nt = 0; nt < 4; ++nt) {
#pragma unroll
            for (int j = 0; j < 8; ++j) {
                int k = ks * 32 + quad * 8 + j;
                ((unsigned short*)&b2[ks][nt])[j] = f2bf(ew2[k * 64 + nt * 16 + l15]);
                if (WRITE_X)
                    ((unsigned short*)&b3[ks][nt])[j] = f2bf(cw1[k * 64 + nt * 16 + l15]);
            }
        }
    __syncthreads();   // only barrier

    float* tW = tWF + wave * 16 * STF;
    const int C  = chunkCnt[0];
    const int gw = blockIdx.x * 4 + wave;
    const int nw = gridDim.x * 4;

    // loop-invariant w1l slice for this lane's k-columns
    float4 wl0 = *(const float4*)&w1ls[quad * 8];
    float4 wl1 = *(const float4*)&w1ls[quad * 8 + 4];
    float4 wl2 = *(const float4*)&w1ls[32 + quad * 8];
    float4 wl3 = *(const float4*)&w1ls[32 + quad * 8 + 4];

    for (int idx = gw; idx < C; idx += nw) {
        const int2 ck = chunkTbl[idx];
        const int n = ck.x;
        const int cs = ck.y & 0x01FFFFFF;
        const int len = ((unsigned)ck.y) >> 25;

        // lanes 0..15: edge metadata
        int s = n; float rad = 0.f, xdx = 0.f, xdy = 0.f, xdz = 0.f;
        if (lane < len) {
            s = srcS[cs + lane];
            float4 xs = x4[s];
            float4 xn = x4[n];
            float dx = xs.x - xn.x;
            float dy = xs.y - xn.y;
            float dz = xs.z - xn.z;
            rad = dx * dx + dy * dy + dz * dz;
            float inv = 1.0f / (sqrtf(rad) + 1e-30f);
            xdx = dx * inv; xdy = dy * inv; xdz = dz * inv;
        }
        const int rowS = __shfl(s, l15);
        const float radL = __shfl(rad, l15);   // this lane's A-row edge radial

        float cxR[4], cyR[4], czR[4]; bool valR[4];
#pragma unroll
        for (int r = 0; r < 4; ++r) {
            int er = quad * 4 + r;
            valR[r] = er < len;
            if (WRITE_X) {
                cxR[r] = __shfl(xdx, er);
                cyR[r] = __shfl(xdy, er);
                czR[r] = __shfl(xdz, er);
            }
        }

        // ---- build t1 A-frags in registers: silu(Ys[src] + Yd[n] + radL*w1l)
        const unsigned short* ps = Ys + (size_t)rowS * 64 + quad * 8;
        bf16x8 g0 = *(const bf16x8*)(ps);
        bf16x8 g1 = *(const bf16x8*)(ps + 32);
        const float* pyd = Yd + (size_t)n * 64 + quad * 8;
        float4 y0 = *(const float4*)(pyd);
        float4 y1 = *(const float4*)(pyd + 4);
        float4 y2 = *(const float4*)(pyd + 32);
        float4 y3 = *(const float4*)(pyd + 36);

        bf16x8 aF0, aF1;
        {
            const unsigned short* pg0 = (const unsigned short*)&g0;
            const unsigned short* pg1 = (const unsigned short*)&g1;
            float t0[8], t1v[8];
            const float* py0 = (const float*)&y0;
            const float* py1 = (const float*)&y1;
            const float* pw0 = (const float*)&wl0;
            const float* pw1 = (const float*)&wl1;
            const float* py2 = (const float*)&y2;
            const float* py3 = (const float*)&y3;
            const float* pw2 = (const float*)&wl2;
            const float* pw3 = (const float*)&wl3;
#pragma unroll
            for (int j = 0; j < 4; ++j) {
                t0[j]      = silu_f(bf2f(pg0[j])     + py0[j] + radL * pw0[j]);
                t0[j + 4]  = silu_f(bf2f(pg0[j + 4]) + py1[j] + radL * pw1[j]);
                t1v[j]     = silu_f(bf2f(pg1[j])     + py2[j] + radL * pw2[j]);
                t1v[j + 4] = silu_f(bf2f(pg1[j + 4]) + py3[j] + radL * pw3[j]);
            }
            unsigned int* pa0 = (unsigned int*)&aF0;
            unsigned int* pa1 = (unsigned int*)&aF1;
#pragma unroll
            for (int j = 0; j < 4; ++j) {
                pa0[j] = f2bf2u(t0[j * 2], t0[j * 2 + 1]);
                pa1[j] = f2bf2u(t1v[j * 2], t1v[j * 2 + 1]);
            }
        }

        // ---- GEMM2: K=64 (B in regs)
        f32x4 acc2[4];
#pragma unroll
        for (int nt = 0; nt < 4; ++nt) acc2[nt] = (f32x4){0.f, 0.f, 0.f, 0.f};
#pragma unroll
        for (int nt = 0; nt < 4; ++nt) {
            acc2[nt] = __builtin_amdgcn_mfma_f32_16x16x32_bf16(aF0, b2[0][nt], acc2[nt], 0, 0, 0);
            acc2[nt] = __builtin_amdgcn_mfma_f32_16x16x32_bf16(aF1, b2[1][nt], acc2[nt], 0, 0, 0);
        }
        // epilogue2: silu -> msg; per-chunk column reduce -> atomics; tW (fp32)
#pragma unroll
        for (int nt = 0; nt < 4; ++nt) {
            int col = nt * 16 + l15;
            float colsum = 0.f;
#pragma unroll
            for (int r = 0; r < 4; ++r) {
                float v = silu_f(acc2[nt][r] + eb2s[col]);
                if (valR[r]) colsum += v;
                if (WRITE_X) tW[(quad * 4 + r) * STF + col] = v;
            }
            colsum += __shfl_xor(colsum, 16);
            colsum += __shfl_xor(colsum, 32);
            if (quad == 0) atomicAdd(&h_neigh[(size_t)n * 64 + col], colsum);
        }
        if (WRITE_X) {
            // GEMM3 A-frags: read fp32 link buf, packed cvt
            bf16x8 aG0, aG1;
            {
                const float* pf = &tW[l15 * STF + quad * 8];
                float4 u0 = *(const float4*)(pf);
                float4 u1 = *(const float4*)(pf + 4);
                float4 u2 = *(const float4*)(pf + 32);
                float4 u3 = *(const float4*)(pf + 36);
                unsigned int* pa0 = (unsigned int*)&aG0;
                unsigned int* pa1 = (unsigned int*)&aG1;
                pa0[0] = f2bf2u(u0.x, u0.y); pa0[1] = f2bf2u(u0.z, u0.w);
                pa0[2] = f2bf2u(u1.x, u1.y); pa0[3] = f2bf2u(u1.z, u1.w);
                pa1[0] = f2bf2u(u2.x, u2.y); pa1[1] = f2bf2u(u2.z, u2.w);
                pa1[2] = f2bf2u(u3.x, u3.y); pa1[3] = f2bf2u(u3.z, u3.w);
            }
            f32x4 acc3[4];
#pragma unroll
            for (int nt = 0; nt < 4; ++nt) acc3[nt] = (f32x4){0.f, 0.f, 0.f, 0.f};
#pragma unroll
            for (int nt = 0; nt < 4; ++nt) {
                acc3[nt] = __builtin_amdgcn_mfma_f32_16x16x32_bf16(aG0, b3[0][nt], acc3[nt], 0, 0, 0);
                acc3[nt] = __builtin_amdgcn_mfma_f32_16x16x32_bf16(aG1, b3[1][nt], acc3[nt], 0, 0, 0);
            }
            float part_[4] = {0.f, 0.f, 0.f, 0.f};
#pragma unroll
            for (int nt = 0; nt < 4; ++nt) {
                int col = nt * 16 + l15;
#pragma unroll
                for (int r = 0; r < 4; ++r)
                    part_[r] += silu_f(acc3[nt][r] + cb1s[col]) * cw2s[col];
            }
            float xc = 0.f;
#pragma unroll
            for (int r = 0; r < 4; ++r) {
                float p = part_[r];
                p += __shfl_xor(p, 1);
                p += __shfl_xor(p, 2);
                p += __shfl_xor(p, 4);
                p += __shfl_xor(p, 8);
                if (valR[r]) {
                    float comp = (l15 == 0) ? cxR[r] : (l15 == 1) ? cyR[r] : czR[r];
                    xc += p * comp;
                }
            }
            xc += __shfl_xor(xc, 16);
            xc += __shfl_xor(xc, 32);
            if (quad == 0 && l15 < 3)
                atomicAdd(&x_sum[(size_t)n * 3 + l15], xc);
        }
    }
}

__global__ void xupd(const float* __restrict__ x_sum, const int* __restrict__ rowptr,
                     const float4* __restrict__ xin, float4* __restrict__ xout) {
    int n = blockIdx.x * 256 + threadIdx.x;
    if (n < NN) {
        float d = (float)(rowptr[n + 1] - rowptr[n]);
        float id = 1.0f / fmaxf(d, 1.0f);
        float4 v = xin[n];
        v.x += x_sum[n * 3 + 0] * id;
        v.y += x_sum[n * 3 + 1] * id;
        v.z += x_sum[n * 3 + 2] * id;
        v.w = 0.f;
        xout[n] = v;
    }
}

// ---------------------------------------------------------------------------
// Node kernel: h_new = silu([h|h_neigh]@NW1+nb1)@NW2+nb2 -> gelu -> LayerNorm.
// ---------------------------------------------------------------------------
template <bool DO_HEAD>
__global__ __launch_bounds__(256, 4) void node_kernel(
    unsigned short* hbf,
    const float* __restrict__ h_nb,   // [N,64] fp32
    const float* __restrict__ nw1,
    const float* __restrict__ nb1,
    const float* __restrict__ nw2,
    const float* __restrict__ nb2,
    const float* __restrict__ ln_g,
    const float* __restrict__ ln_b,
    const float* __restrict__ out_w,  // [64,32]
    const float* __restrict__ out_b,  // [32]
    float* __restrict__ out)          // [N,32]
{
    __shared__ __align__(16) unsigned short w1T[64 * SW];
    __shared__ __align__(16) unsigned short w2T[64 * ST];
    __shared__ __align__(16) unsigned short tAll[4 * 16 * ST];
    __shared__ float nb1s[64], nb2s[64], gs[64], bs[64], obs[32];

    const int tid  = threadIdx.x;
    const int wave = tid >> 6;
    const int lane = tid & 63;
    const int quad = lane >> 4;
    const int l15  = lane & 15;

    for (int i = tid; i < 64 * 128; i += 256) {
        int n = i & 63, k = i >> 6;
        w1T[n * SW + k] = f2bf(nw1[k * 64 + n]);
    }
    for (int i = tid; i < 64 * 64; i += 256) {
        int n = i & 63, k = i >> 6;
        w2T[n * ST + k] = f2bf(nw2[k * 64 + n]);
    }
    if (tid < 64) {
        nb1s[tid] = nb1[tid]; nb2s[tid] = nb2[tid];
        gs[tid] = ln_g[tid]; bs[tid] = ln_b[tid];
        if (DO_HEAD && tid < 32) obs[tid] = out_b[tid];
    }
    bf16x8 b3[2][2];
    if (DO_HEAD) {
#pragma unroll
        for (int ks = 0; ks < 2; ++ks)
#pragma unroll
            for (int nt = 0; nt < 2; ++nt) {
#pragma unroll
                for (int j = 0; j < 8; ++j) {
                    int k = ks * 32 + quad * 8 + j;
                    ((unsigned short*)&b3[ks][nt])[j] = f2bf(out_w[k * 32 + nt * 16 + l15]);
                }
            }
    }
    __syncthreads();

    unsigned short* tW = tAll + wave * 16 * ST;

    for (int t = blockIdx.x * 4 + wave; t < NN / 16; t += gridDim.x * 4) {
        const int n0 = t * 16;
        const int myRow = n0 + l15;
        const unsigned short* ph = hbf + (size_t)myRow * 64 + quad * 8;
        bf16x8 a0 = *(const bf16x8*)(ph);
        bf16x8 a1 = *(const bf16x8*)(ph + 32);
        bf16x8 a2, a3;
        {
            const float* pb = h_nb + (size_t)myRow * 64 + quad * 8;
            float4 v0 = *(const float4*)(pb);
            float4 v1 = *(const float4*)(pb + 4);
            float4 v2 = *(const float4*)(pb + 32);
            float4 v3 = *(const float4*)(pb + 36);
            unsigned int* pa2 = (unsigned int*)&a2;
            unsigned int* pa3 = (unsigned int*)&a3;
            pa2[0] = f2bf2u(v0.x, v0.y); pa2[1] = f2bf2u(v0.z, v0.w);
            pa2[2] = f2bf2u(v1.x, v1.y); pa2[3] = f2bf2u(v1.z, v1.w);
            pa3[0] = f2bf2u(v2.x, v2.y); pa3[1] = f2bf2u(v2.z, v2.w);
            pa3[2] = f2bf2u(v3.x, v3.y); pa3[3] = f2bf2u(v3.z, v3.w);
        }

        f32x4 acc[4];
#pragma unroll
        for (int nt = 0; nt < 4; ++nt) acc[nt] = (f32x4){0.f, 0.f, 0.f, 0.f};
        {
            const unsigned short* bBase = &w1T[l15 * SW + quad * 8];
#pragma unroll
            for (int nt = 0; nt < 4; ++nt) {
                const unsigned short* bb = bBase + nt * 16 * SW;
                acc[nt] = __builtin_amdgcn_mfma_f32_16x16x32_bf16(a0, *(const bf16x8*)(bb), acc[nt], 0, 0, 0);
                acc[nt] = __builtin_amdgcn_mfma_f32_16x16x32_bf16(a1, *(const bf16x8*)(bb + 32), acc[nt], 0, 0, 0);
                acc[nt] = __builtin_amdgcn_mfma_f32_16x16x32_bf16(a2, *(const bf16x8*)(bb + 64), acc[nt], 0, 0, 0);
                acc[nt] = __builtin_amdgcn_mfma_f32_16x16x32_bf16(a3, *(const bf16x8*)(bb + 96), acc[nt], 0, 0, 0);
            }
        }
#pragma unroll
        for (int nt = 0; nt < 4; ++nt) {
            int col = nt * 16 + l15;
#pragma unroll
            for (int r = 0; r < 4; ++r) {
                float v = acc[nt][r] + nb1s[col];
                tW[(quad * 4 + r) * ST + col] = f2bf(silu_f(v));
            }
        }
        f32x4 acc2[4];
#pragma unroll
        for (int nt = 0; nt < 4; ++nt) acc2[nt] = (f32x4){0.f, 0.f, 0.f, 0.f};
        {
            bf16x8 ax0 = *(const bf16x8*)&tW[l15 * ST + quad * 8];
            bf16x8 ax1 = *(const bf16x8*)&tW[l15 * ST + 32 + quad * 8];
            const unsigned short* bBase = &w2T[l15 * ST + quad * 8];
#pragma unroll
            for (int nt = 0; nt < 4; ++nt) {
                const unsigned short* bb = bBase + nt * 16 * ST;
                acc2[nt] = __builtin_amdgcn_mfma_f32_16x16x32_bf16(ax0, *(const bf16x8*)(bb), acc2[nt], 0, 0, 0);
                acc2[nt] = __builtin_amdgcn_mfma_f32_16x16x32_bf16(ax1, *(const bf16x8*)(bb + 32), acc2[nt], 0, 0, 0);
            }
        }
        float vals[4][4];
        float sum[4] = {0.f, 0.f, 0.f, 0.f}, ss[4] = {0.f, 0.f, 0.f, 0.f};
#pragma unroll
        for (int nt = 0; nt < 4; ++nt) {
            int col = nt * 16 + l15;
#pragma unroll
            for (int r = 0; r < 4; ++r) {
                float v = acc2[nt][r] + nb2s[col];
                float g = 0.5f * v * (1.0f + erff(v * 0.70710678118654752f));
                vals[nt][r] = g;
                sum[r] += g;
                ss[r] += g * g;
            }
        }
#pragma unroll
        for (int r = 0; r < 4; ++r) {
            float s1 = sum[r], s2 = ss[r];
            s1 += __shfl_xor(s1, 1); s2 += __shfl_xor(s2, 1);
            s1 += __shfl_xor(s1, 2); s2 += __shfl_xor(s2, 2);
            s1 += __shfl_xor(s1, 4); s2 += __shfl_xor(s2, 4);
            s1 += __shfl_xor(s1, 8); s2 += __shfl_xor(s2, 8);
            sum[r] = s1; ss[r] = s2;
        }
#pragma unroll
        for (int r = 0; r < 4; ++r) {
            float mean = sum[r] * (1.0f / 64.0f);
            float var  = ss[r] * (1.0f / 64.0f) - mean * mean;
            float rstd = rsqrtf(var + 1e-5f);
            int n = n0 + quad * 4 + r;
#pragma unroll
            for (int nt = 0; nt < 4; ++nt) {
                int col = nt * 16 + l15;
                float y = (vals[nt][r] - mean) * rstd * gs[col] + bs[col];
                if (DO_HEAD) tW[(quad * 4 + r) * ST + col] = f2bf(y);
                else hbf[(size_t)n * 64 + col] = f2bf(y);
            }
        }
        if (DO_HEAD) {
            f32x4 accH[2];
#pragma unroll
            for (int nt = 0; nt < 2; ++nt) accH[nt] = (f32x4){0.f, 0.f, 0.f, 0.f};
            bf16x8 ax0 = *(const bf16x8*)&tW[l15 * ST + quad * 8];
            bf16x8 ax1 = *(const bf16x8*)&tW[l15 * ST + 32 + quad * 8];
#pragma unroll
            for (int nt = 0; nt < 2; ++nt) {
                accH[nt] = __builtin_amdgcn_mfma_f32_16x16x32_bf16(ax0, b3[0][nt], accH[nt], 0, 0, 0);
                accH[nt] = __builtin_amdgcn_mfma_f32_16x16x32_bf16(ax1, b3[1][nt], accH[nt], 0, 0, 0);
            }
#pragma unroll
            for (int nt = 0; nt < 2; ++nt) {
                int col = nt * 16 + l15;
#pragma unroll
                for (int r = 0; r < 4; ++r)
                    out[(size_t)(n0 + quad * 4 + r) * 32 + col] = accH[nt][r] + obs[col];
            }
        }
    }
}

__global__ void init_h(const float* __restrict__ nf, unsigned short* __restrict__ hbf) {
    int i = blockIdx.x * 256 + threadIdx.x;
    if (i < NN * 64) hbf[i] = f2bf(nf[i]);
}
__global__ void init_x(const float* __restrict__ xyz, float4* __restrict__ x4) {
    int n = blockIdx.x * 256 + threadIdx.x;
    if (n < NN) {
        float4 v;
        v.x = xyz[n * 3 + 0]; v.y = xyz[n * 3 + 1]; v.z = xyz[n * 3 + 2]; v.w = 0.f;
        x4[n] = v;
    }
}

extern "C" void kernel_launch(void* const* d_in, const int* in_sizes, int n_in,
                              void* d_out, int out_size, void* d_ws, size_t ws_size,
                              hipStream_t stream)
{
    const float* node_feat = (const float*)d_in[0];
    const float* xyz   = (const float*)d_in[1];
    const int*   src   = (const int*)d_in[2];
    const int*   dst   = (const int*)d_in[3];
    const float* ew1   = (const float*)d_in[4];
    const float* eb1   = (const float*)d_in[5];
    const float* ew2   = (const float*)d_in[6];
    const float* eb2   = (const float*)d_in[7];
    const float* cw1   = (const float*)d_in[8];
    const float* cb1   = (const float*)d_in[9];
    const float* cw2   = (const float*)d_in[10];
    const float* nw1   = (const float*)d_in[11];
    const float* nb1   = (const float*)d_in[12];
    const float* nw2   = (const float*)d_in[13];
    const float* nb2   = (const float*)d_in[14];
    const float* ln_g  = (const float*)d_in[15];
    const float* ln_b  = (const float*)d_in[16];
    const float* out_w = (const float*)d_in[17];
    const float* out_b = (const float*)d_in[18];
    float* out = (float*)d_out;

    char* ws = (char*)d_ws;
    float* h_neigh = (float*)ws;                 ws += (size_t)NN * 64 * 4;
    unsigned short* hbf = (unsigned short*)ws;   ws += (size_t)NN * 64 * 2;
    unsigned short* Ys  = (unsigned short*)ws;   ws += (size_t)NN * 64 * 2;
    float* Yd     = (float*)ws;                  ws += (size_t)NN * 64 * 4;
    float4* xA    = (float4*)ws;                 ws += (size_t)NN * 16;
    float4* xB    = (float4*)ws;                 ws += (size_t)NN * 16;
    float* x_sum  = (float*)ws;                  ws += (size_t)NN * 3 * 4;
    int* rowptr   = (int*)ws;                    ws += (size_t)(NN + 1) * 4;
    int* chunkPtr = (int*)ws;                    ws += (size_t)(NN + 1) * 4;
    int* counts   = (int*)ws;                    ws += (size_t)NN * 4;   // reused as cursor
    int* srcS     = (int*)ws;                    ws += (size_t)NE * 4;
    int2* chunkTbl = (int2*)ws;                  ws += (size_t)(NN + NE / 16) * 8;
    int2* blockTot = (int2*)ws;                  ws += (size_t)SCAN_BLK * 8;

    hipMemsetAsync(counts, 0, (size_t)NN * 4, stream);
    init_h<<<(NN * 64 + 255) / 256, 256, 0, stream>>>(node_feat, hbf);
    init_x<<<(NN + 255) / 256, 256, 0, stream>>>(xyz, xA);
    hist_kernel<<<(NE + 255) / 256, 256, 0, stream>>>(dst, counts);
    scanA<<<SCAN_BLK, 256, 0, stream>>>(counts, blockTot);
    scanB<<<1, 128, 0, stream>>>(blockTot, rowptr, chunkPtr);
    scanC<<<SCAN_BLK, 256, 0, stream>>>(counts, blockTot, rowptr, counts, chunkPtr);
    scatter_kernel<<<(NE + 255) / 256, 256, 0, stream>>>(src, dst, counts, srcS);
    fill_chunks<<<(NN + 255) / 256, 256, 0, stream>>>(rowptr, chunkPtr, chunkTbl);

    // ---- layer 0 (computes x for layer 1)
    hipMemsetAsync(h_neigh, 0, (size_t)NN * 64 * 4, stream);
    hipMemsetAsync(x_sum, 0, (size_t)NN * 3 * 4, stream);
    prep_kernel<<<1024, 256, 0, stream>>>(hbf, ew1, eb1, Ys, Yd);
    edge5_kernel<true, 3><<<2048, 256, 0, stream>>>(
        xA, Ys, Yd, srcS, chunkTbl, chunkPtr + NN,
        ew1, ew2, eb2, cw1, cb1, cw2, h_neigh, x_sum);
    xupd<<<(NN + 255) / 256, 256, 0, stream>>>(x_sum, rowptr, xA, xB);
    node_kernel<false><<<1024, 256, 0, stream>>>(
        hbf, h_neigh, nw1, nb1, nw2, nb2, ln_g, ln_b, out_w, out_b, out);

    // ---- layer 1 (x output dead -> no coord head; head fused into node kernel)
    hipMemsetAsync(h_neigh, 0, (size_t)NN * 64 * 4, stream);
    prep_kernel<<<1024, 256, 0, stream>>>(hbf, ew1 + 129 * 64, eb1 + 64, Ys, Yd);
    edge5_kernel<false, 4><<<2048, 256, 0, stream>>>(
        xB, Ys, Yd, srcS, chunkTbl, chunkPtr + NN,
        ew1 + 129 * 64, ew2 + 64 * 64, eb2 + 64, cw1 + 64 * 64, cb1 + 64, cw2 + 64,
        h_neigh, nullptr);
    node_kernel<true><<<1024, 256, 0, stream>>>(
        hbf, h_neigh, nw1 + 128 * 64, nb1 + 64, nw2 + 64 * 64, nb2 + 64,
        ln_g, ln_b, out_w, out_b, out);
}

// Round 9
// 781.438 us; speedup vs baseline: 3.0283x; 1.2269x over previous
//
#include <hip/hip_runtime.h>
#include <hip/hip_bf16.h>

#define NN 100000
#define NE 1600000
#define SW 136   // padded stride (shorts) for [64][128] bf16 weight tiles
#define ST 68    // padded stride (shorts) for [16][64] bf16 link tiles
#define STF 68   // padded stride (floats) for fp32 link tiles

typedef __attribute__((ext_vector_type(8))) short bf16x8;
typedef __attribute__((ext_vector_type(4))) float f32x4;

__device__ __forceinline__ unsigned short f2bf(float f) {
    union { float f; unsigned int u; } v; v.f = f;
    unsigned int u = v.u + 0x7fff + ((v.u >> 16) & 1);
    return (unsigned short)(u >> 16);
}
__device__ __forceinline__ unsigned int f2bf2u(float a, float b) {
    union { __hip_bfloat162 h; unsigned int u; } cv;
    cv.h = __float22bfloat162_rn(make_float2(a, b));
    return cv.u;
}
__device__ __forceinline__ float bf2f(unsigned short h) {
    union { unsigned int u; float f; } v; v.u = ((unsigned int)h) << 16;
    return v.f;
}
// fast silu: v * rcp(1+exp(-v)) — avoids IEEE div sequence (~10 VALU -> ~3)
__device__ __forceinline__ float silu_f(float v) {
    return v * __builtin_amdgcn_rcpf(1.0f + __expf(-v));
}

// ---------------- CSR + chunk-table build (parallel scan) ----------------
__global__ void hist_kernel(const int* __restrict__ dst, int* __restrict__ counts) {
    int i = blockIdx.x * 256 + threadIdx.x;
    if (i < NE) atomicAdd(&counts[dst[i]], 1);
}

#define SCAN_BLK ((NN + 1023) / 1024)   // 98 blocks, 1024 nodes each

__global__ __launch_bounds__(256) void scanA(const int* __restrict__ counts,
                                             int2* __restrict__ blockTot) {
    __shared__ int sS[256], sC[256];
    int tid = threadIdx.x;
    int base = blockIdx.x * 1024 + tid * 4;
    int s = 0, c = 0;
#pragma unroll
    for (int j = 0; j < 4; ++j) {
        int idx = base + j;
        if (idx < NN) { int v = counts[idx]; s += v; c += (v + 15) >> 4; }
    }
    sS[tid] = s; sC[tid] = c;
    __syncthreads();
    for (int off = 128; off > 0; off >>= 1) {
        if (tid < off) { sS[tid] += sS[tid + off]; sC[tid] += sC[tid + off]; }
        __syncthreads();
    }
    if (tid == 0) blockTot[blockIdx.x] = make_int2(sS[0], sC[0]);
}

__global__ __launch_bounds__(128) void scanB(int2* __restrict__ blockTot,
                                             int* __restrict__ rowptr,
                                             int* __restrict__ chunkPtr) {
    __shared__ int sS[128], sC[128];
    int tid = threadIdx.x;
    int2 v = (tid < SCAN_BLK) ? blockTot[tid] : make_int2(0, 0);
    sS[tid] = v.x; sC[tid] = v.y;
    __syncthreads();
    for (int off = 1; off < 128; off <<= 1) {
        int aS = sS[tid], aC = sC[tid];
        int bS = (tid >= off) ? sS[tid - off] : 0;
        int bC = (tid >= off) ? sC[tid - off] : 0;
        __syncthreads();
        sS[tid] = aS + bS; sC[tid] = aC + bC;
        __syncthreads();
    }
    if (tid < SCAN_BLK) blockTot[tid] = make_int2(sS[tid] - v.x, sC[tid] - v.y); // exclusive
    if (tid == 127) { rowptr[NN] = sS[127]; chunkPtr[NN] = sC[127]; }
}

__global__ __launch_bounds__(256) void scanC(const int* __restrict__ counts,
                                             const int2* __restrict__ blockTot,
                                             int* __restrict__ rowptr,
                                             int* __restrict__ cursor,
                                             int* __restrict__ chunkPtr) {
    __shared__ int sS[256], sC[256];
    int tid = threadIdx.x;
    int base = blockIdx.x * 1024 + tid * 4;
    int vloc[4]; int s = 0, c = 0;
#pragma unroll
    for (int j = 0; j < 4; ++j) {
        int idx = base + j;
        vloc[j] = (idx < NN) ? counts[idx] : 0;
        s += vloc[j]; c += (vloc[j] + 15) >> 4;
    }
    sS[tid] = s; sC[tid] = c;
    __syncthreads();
    for (int off = 1; off < 256; off <<= 1) {
        int aS = sS[tid], aC = sC[tid];
        int bS = (tid >= off) ? sS[tid - off] : 0;
        int bC = (tid >= off) ? sC[tid - off] : 0;
        __syncthreads();
        sS[tid] = aS + bS; sC[tid] = aC + bC;
        __syncthreads();
    }
    int2 bo = blockTot[blockIdx.x];
    int runS = bo.x + sS[tid] - s;
    int runC = bo.y + sC[tid] - c;
#pragma unroll
    for (int j = 0; j < 4; ++j) {
        int idx = base + j;
        if (idx < NN) {
            rowptr[idx] = runS; cursor[idx] = runS; chunkPtr[idx] = runC;
            runS += vloc[j]; runC += (vloc[j] + 15) >> 4;
        }
    }
}

__global__ void scatter_kernel(const int* __restrict__ src, const int* __restrict__ dst,
                               int* __restrict__ cursor, int* __restrict__ srcS) {
    int i = blockIdx.x * 256 + threadIdx.x;
    if (i < NE) {
        int pos = atomicAdd(&cursor[dst[i]], 1);
        srcS[pos] = src[i];
    }
}

// chunkTbl entry: (n, cs | len<<25), len in [1,16]
__global__ void fill_chunks(const int* __restrict__ rowptr, const int* __restrict__ chunkPtr,
                            int2* __restrict__ chunkTbl) {
    int n = blockIdx.x * 256 + threadIdx.x;
    if (n < NN) {
        int s = rowptr[n], e = rowptr[n + 1];
        int b = chunkPtr[n];
        for (int cs = s, i = 0; cs < e; cs += 16, ++i) {
            int len = min(16, e - cs);
            chunkTbl[b + i] = make_int2(n, cs | (len << 25));
        }
    }
}

// ---------------------------------------------------------------------------
// Prep kernel: per node, Ys = h@W1[0:64] (bf16), Yd = h@W1[64:128]+eb1 (fp32).
// ---------------------------------------------------------------------------
__global__ __launch_bounds__(256, 4) void prep_kernel(
    const unsigned short* __restrict__ hbf,
    const float* __restrict__ ew1,   // [129,64]
    const float* __restrict__ eb1,
    unsigned short* __restrict__ Ys, // [N,64] bf16
    float* __restrict__ Yd)          // [N,64] fp32
{
    __shared__ __align__(16) unsigned short w1sT[64 * ST];
    __shared__ __align__(16) unsigned short w1dT[64 * ST];
    __shared__ float eb1s[64];

    const int tid  = threadIdx.x;
    const int wave = __builtin_amdgcn_readfirstlane(tid >> 6);
    const int lane = tid & 63;
    const int quad = lane >> 4;
    const int l15  = lane & 15;

    for (int i = tid; i < 64 * 64; i += 256) {
        int n = i & 63, k = i >> 6;
        w1sT[n * ST + k] = f2bf(ew1[k * 64 + n]);
        w1dT[n * ST + k] = f2bf(ew1[(64 + k) * 64 + n]);
    }
    if (tid < 64) eb1s[tid] = eb1[tid];
    __syncthreads();

    for (int t = blockIdx.x * 4 + wave; t < NN / 16; t += gridDim.x * 4) {
        const int n0 = t * 16;
        const unsigned short* ph = hbf + (size_t)(n0 + l15) * 64 + quad * 8;
        bf16x8 a0 = *(const bf16x8*)(ph);
        bf16x8 a1 = *(const bf16x8*)(ph + 32);

        f32x4 accS[4], accD[4];
#pragma unroll
        for (int nt = 0; nt < 4; ++nt) {
            accS[nt] = (f32x4){0.f, 0.f, 0.f, 0.f};
            accD[nt] = (f32x4){0.f, 0.f, 0.f, 0.f};
        }
        const unsigned short* bS = &w1sT[l15 * ST + quad * 8];
        const unsigned short* bD = &w1dT[l15 * ST + quad * 8];
#pragma unroll
        for (int nt = 0; nt < 4; ++nt) {
            const unsigned short* bbS = bS + nt * 16 * ST;
            const unsigned short* bbD = bD + nt * 16 * ST;
            accS[nt] = __builtin_amdgcn_mfma_f32_16x16x32_bf16(a0, *(const bf16x8*)(bbS), accS[nt], 0, 0, 0);
            accS[nt] = __builtin_amdgcn_mfma_f32_16x16x32_bf16(a1, *(const bf16x8*)(bbS + 32), accS[nt], 0, 0, 0);
            accD[nt] = __builtin_amdgcn_mfma_f32_16x16x32_bf16(a0, *(const bf16x8*)(bbD), accD[nt], 0, 0, 0);
            accD[nt] = __builtin_amdgcn_mfma_f32_16x16x32_bf16(a1, *(const bf16x8*)(bbD + 32), accD[nt], 0, 0, 0);
        }
#pragma unroll
        for (int nt = 0; nt < 4; ++nt) {
            int col = nt * 16 + l15;
#pragma unroll
            for (int r = 0; r < 4; ++r) {
                int n = n0 + quad * 4 + r;
                Ys[(size_t)n * 64 + col] = f2bf(accS[nt][r]);
                Yd[(size_t)n * 64 + col] = accD[nt][r] + eb1s[col];
            }
        }
    }
}

// ---------------------------------------------------------------------------
// Edge kernel v6: chunk-parallel, stateless body, scalarized uniforms:
//  - idx wave-uniform (readfirstlane wave) -> chunkTbl via s_load;
//  - n scalar -> Yd/x4[n]/h_neigh/x_sum SGPR-base addressing;
//  - every lane loads srcS[cs+l15] (line-broadcast) and computes rad for its
//    own A-row directly: no metadata bpermutes;
//  - fast silu (rcp), fast sqrt; B-frags in registers.
// ---------------------------------------------------------------------------
template <bool WRITE_X, int MINW>
__global__ __launch_bounds__(256, MINW) void edge6_kernel(
    const float4* __restrict__ x4,
    const unsigned short* __restrict__ Ys,
    const float* __restrict__ Yd,
    const int* __restrict__ srcS,
    const int2* __restrict__ chunkTbl,
    const int* __restrict__ chunkCnt,
    const float* __restrict__ ew1,   // for w1l = row 128
    const float* __restrict__ ew2,   // [64,64]
    const float* __restrict__ eb2,
    const float* __restrict__ cw1,   // [64,64]
    const float* __restrict__ cb1,
    const float* __restrict__ cw2,   // [64]
    float* __restrict__ h_neigh,     // [N,64] fp32 (pre-zeroed)
    float* __restrict__ x_sum)       // [N,3] fp32 (pre-zeroed, WRITE_X only)
{
    constexpr int TWN = WRITE_X ? (4 * 16 * STF) : 4;
    __shared__ __align__(16) float tWF[TWN];       // per-wave fp32 link buf (layer0)
    __shared__ __align__(16) float w1ls[64];
    __shared__ float eb2s[64], cb1s[64], cw2s[64];

    const int tid  = threadIdx.x;
    const int wave = __builtin_amdgcn_readfirstlane(tid >> 6);
    const int lane = tid & 63;
    const int quad = lane >> 4;
    const int l15  = lane & 15;

    if (tid < 64) {
        eb2s[tid] = eb2[tid]; cb1s[tid] = cb1[tid];
        cw2s[tid] = cw2[tid]; w1ls[tid] = ew1[128 * 64 + tid];
    }
    // B-frags from global, once per block (loop-invariant registers)
    bf16x8 b2[2][4], b3[2][4];
#pragma unroll
    for (int ks = 0; ks < 2; ++ks)
#pragma unroll
        for (int nt = 0; nt < 4; ++nt) {
#pragma unroll
            for (int j = 0; j < 8; ++j) {
                int k = ks * 32 + quad * 8 + j;
                ((unsigned short*)&b2[ks][nt])[j] = f2bf(ew2[k * 64 + nt * 16 + l15]);
                if (WRITE_X)
                    ((unsigned short*)&b3[ks][nt])[j] = f2bf(cw1[k * 64 + nt * 16 + l15]);
            }
        }
    __syncthreads();   // only barrier

    float* tW = tWF + wave * 16 * STF;
    const int C  = chunkCnt[0];
    const int gw = blockIdx.x * 4 + wave;
    const int nw = gridDim.x * 4;

    // loop-invariant w1l slice for this lane's k-columns
    float4 wl0 = *(const float4*)&w1ls[quad * 8];
    float4 wl1 = *(const float4*)&w1ls[quad * 8 + 4];
    float4 wl2 = *(const float4*)&w1ls[32 + quad * 8];
    float4 wl3 = *(const float4*)&w1ls[32 + quad * 8 + 4];

    for (int idx = gw; idx < C; idx += nw) {
        // idx is wave-uniform -> scalar load
        const int2 ck = chunkTbl[idx];
        const int n   = __builtin_amdgcn_readfirstlane(ck.x);
        const int cky = __builtin_amdgcn_readfirstlane(ck.y);
        const int cs  = cky & 0x01FFFFFF;
        const int len = ((unsigned)cky) >> 25;

        // every lane: src + rad for its own A-row (edge l15); line-broadcast load
        const int s = srcS[cs + ((l15 < len) ? l15 : 0)];
        const float4 xn = x4[n];            // scalar-base, wave-uniform
        const float4 xs = x4[s];
        const float dx = xs.x - xn.x;
        const float dy = xs.y - xn.y;
        const float dz = xs.z - xn.z;
        const float radL = dx * dx + dy * dy + dz * dz;
        float xdx = 0.f, xdy = 0.f, xdz = 0.f;
        if (WRITE_X) {
            float inv = __builtin_amdgcn_rcpf(__builtin_amdgcn_sqrtf(radL) + 1e-30f);
            xdx = dx * inv; xdy = dy * inv; xdz = dz * inv;
        }

        float cxR[4], cyR[4], czR[4]; bool valR[4];
#pragma unroll
        for (int r = 0; r < 4; ++r) {
            int er = quad * 4 + r;
            valR[r] = er < len;
            if (WRITE_X) {
                cxR[r] = __shfl(xdx, er);
                cyR[r] = __shfl(xdy, er);
                czR[r] = __shfl(xdz, er);
            }
        }

        // ---- build t1 A-frags in registers: silu(Ys[src] + Yd[n] + radL*w1l)
        const unsigned short* ps = Ys + (size_t)s * 64 + quad * 8;
        bf16x8 g0 = *(const bf16x8*)(ps);
        bf16x8 g1 = *(const bf16x8*)(ps + 32);
        const float* pyd = Yd + (size_t)n * 64 + quad * 8;   // scalar base
        float4 y0 = *(const float4*)(pyd);
        float4 y1 = *(const float4*)(pyd + 4);
        float4 y2 = *(const float4*)(pyd + 32);
        float4 y3 = *(const float4*)(pyd + 36);

        bf16x8 aF0, aF1;
        {
            const unsigned short* pg0 = (const unsigned short*)&g0;
            const unsigned short* pg1 = (const unsigned short*)&g1;
            float t0[8], t1v[8];
            const float* py0 = (const float*)&y0;
            const float* py1 = (const float*)&y1;
            const float* pw0 = (const float*)&wl0;
            const float* pw1 = (const float*)&wl1;
            const float* py2 = (const float*)&y2;
            const float* py3 = (const float*)&y3;
            const float* pw2 = (const float*)&wl2;
            const float* pw3 = (const float*)&wl3;
#pragma unroll
            for (int j = 0; j < 4; ++j) {
                t0[j]      = silu_f(bf2f(pg0[j])     + py0[j] + radL * pw0[j]);
                t0[j + 4]  = silu_f(bf2f(pg0[j + 4]) + py1[j] + radL * pw1[j]);
                t1v[j]     = silu_f(bf2f(pg1[j])     + py2[j] + radL * pw2[j]);
                t1v[j + 4] = silu_f(bf2f(pg1[j + 4]) + py3[j] + radL * pw3[j]);
            }
            unsigned int* pa0 = (unsigned int*)&aF0;
            unsigned int* pa1 = (unsigned int*)&aF1;
#pragma unroll
            for (int j = 0; j < 4; ++j) {
                pa0[j] = f2bf2u(t0[j * 2], t0[j * 2 + 1]);
                pa1[j] = f2bf2u(t1v[j * 2], t1v[j * 2 + 1]);
            }
        }

        // ---- GEMM2: K=64 (B in regs)
        f32x4 acc2[4];
#pragma unroll
        for (int nt = 0; nt < 4; ++nt) acc2[nt] = (f32x4){0.f, 0.f, 0.f, 0.f};
#pragma unroll
        for (int nt = 0; nt < 4; ++nt) {
            acc2[nt] = __builtin_amdgcn_mfma_f32_16x16x32_bf16(aF0, b2[0][nt], acc2[nt], 0, 0, 0);
            acc2[nt] = __builtin_amdgcn_mfma_f32_16x16x32_bf16(aF1, b2[1][nt], acc2[nt], 0, 0, 0);
        }
        // epilogue2: silu -> msg; per-chunk column reduce -> atomics; tW (fp32)
#pragma unroll
        for (int nt = 0; nt < 4; ++nt) {
            int col = nt * 16 + l15;
            float colsum = 0.f;
#pragma unroll
            for (int r = 0; r < 4; ++r) {
                float v = silu_f(acc2[nt][r] + eb2s[col]);
                if (valR[r]) colsum += v;
                if (WRITE_X) tW[(quad * 4 + r) * STF + col] = v;
            }
            colsum += __shfl_xor(colsum, 16);
            colsum += __shfl_xor(colsum, 32);
            if (quad == 0) atomicAdd(&h_neigh[(size_t)n * 64 + col], colsum);
        }
        if (WRITE_X) {
            // GEMM3 A-frags: read fp32 link buf, packed cvt
            bf16x8 aG0, aG1;
            {
                const float* pf = &tW[l15 * STF + quad * 8];
                float4 u0 = *(const float4*)(pf);
                float4 u1 = *(const float4*)(pf + 4);
                float4 u2 = *(const float4*)(pf + 32);
                float4 u3 = *(const float4*)(pf + 36);
                unsigned int* pa0 = (unsigned int*)&aG0;
                unsigned int* pa1 = (unsigned int*)&aG1;
                pa0[0] = f2bf2u(u0.x, u0.y); pa0[1] = f2bf2u(u0.z, u0.w);
                pa0[2] = f2bf2u(u1.x, u1.y); pa0[3] = f2bf2u(u1.z, u1.w);
                pa1[0] = f2bf2u(u2.x, u2.y); pa1[1] = f2bf2u(u2.z, u2.w);
                pa1[2] = f2bf2u(u3.x, u3.y); pa1[3] = f2bf2u(u3.z, u3.w);
            }
            f32x4 acc3[4];
#pragma unroll
            for (int nt = 0; nt < 4; ++nt) acc3[nt] = (f32x4){0.f, 0.f, 0.f, 0.f};
#pragma unroll
            for (int nt = 0; nt < 4; ++nt) {
                acc3[nt] = __builtin_amdgcn_mfma_f32_16x16x32_bf16(aG0, b3[0][nt], acc3[nt], 0, 0, 0);
                acc3[nt] = __builtin_amdgcn_mfma_f32_16x16x32_bf16(aG1, b3[1][nt], acc3[nt], 0, 0, 0);
            }
            float part_[4] = {0.f, 0.f, 0.f, 0.f};
#pragma unroll
            for (int nt = 0; nt < 4; ++nt) {
                int col = nt * 16 + l15;
#pragma unroll
                for (int r = 0; r < 4; ++r)
                    part_[r] += silu_f(acc3[nt][r] + cb1s[col]) * cw2s[col];
            }
            float xc = 0.f;
#pragma unroll
            for (int r = 0; r < 4; ++r) {
                float p = part_[r];
                p += __shfl_xor(p, 1);
                p += __shfl_xor(p, 2);
                p += __shfl_xor(p, 4);
                p += __shfl_xor(p, 8);
                if (valR[r]) {
                    float comp = (l15 == 0) ? cxR[r] : (l15 == 1) ? cyR[r] : czR[r];
                    xc += p * comp;
                }
            }
            xc += __shfl_xor(xc, 16);
            xc += __shfl_xor(xc, 32);
            if (quad == 0 && l15 < 3)
                atomicAdd(&x_sum[(size_t)n * 3 + l15], xc);
        }
    }
}

__global__ void xupd(const float* __restrict__ x_sum, const int* __restrict__ rowptr,
                     const float4* __restrict__ xin, float4* __restrict__ xout) {
    int n = blockIdx.x * 256 + threadIdx.x;
    if (n < NN) {
        float d = (float)(rowptr[n + 1] - rowptr[n]);
        float id = __builtin_amdgcn_rcpf(fmaxf(d, 1.0f));
        float4 v = xin[n];
        v.x += x_sum[n * 3 + 0] * id;
        v.y += x_sum[n * 3 + 1] * id;
        v.z += x_sum[n * 3 + 2] * id;
        v.w = 0.f;
        xout[n] = v;
    }
}

// ---------------------------------------------------------------------------
// Node kernel: h_new = silu([h|h_neigh]@NW1+nb1)@NW2+nb2 -> gelu -> LayerNorm.
// ---------------------------------------------------------------------------
template <bool DO_HEAD>
__global__ __launch_bounds__(256, 4) void node_kernel(
    unsigned short* hbf,
    const float* __restrict__ h_nb,   // [N,64] fp32
    const float* __restrict__ nw1,
    const float* __restrict__ nb1,
    const float* __restrict__ nw2,
    const float* __restrict__ nb2,
    const float* __restrict__ ln_g,
    const float* __restrict__ ln_b,
    const float* __restrict__ out_w,  // [64,32]
    const float* __restrict__ out_b,  // [32]
    float* __restrict__ out)          // [N,32]
{
    __shared__ __align__(16) unsigned short w1T[64 * SW];
    __shared__ __align__(16) unsigned short w2T[64 * ST];
    __shared__ __align__(16) unsigned short tAll[4 * 16 * ST];
    __shared__ float nb1s[64], nb2s[64], gs[64], bs[64], obs[32];

    const int tid  = threadIdx.x;
    const int wave = __builtin_amdgcn_readfirstlane(tid >> 6);
    const int lane = tid & 63;
    const int quad = lane >> 4;
    const int l15  = lane & 15;

    for (int i = tid; i < 64 * 128; i += 256) {
        int n = i & 63, k = i >> 6;
        w1T[n * SW + k] = f2bf(nw1[k * 64 + n]);
    }
    for (int i = tid; i < 64 * 64; i += 256) {
        int n = i & 63, k = i >> 6;
        w2T[n * ST + k] = f2bf(nw2[k * 64 + n]);
    }
    if (tid < 64) {
        nb1s[tid] = nb1[tid]; nb2s[tid] = nb2[tid];
        gs[tid] = ln_g[tid]; bs[tid] = ln_b[tid];
        if (DO_HEAD && tid < 32) obs[tid] = out_b[tid];
    }
    bf16x8 b3[2][2];
    if (DO_HEAD) {
#pragma unroll
        for (int ks = 0; ks < 2; ++ks)
#pragma unroll
            for (int nt = 0; nt < 2; ++nt) {
#pragma unroll
                for (int j = 0; j < 8; ++j) {
                    int k = ks * 32 + quad * 8 + j;
                    ((unsigned short*)&b3[ks][nt])[j] = f2bf(out_w[k * 32 + nt * 16 + l15]);
                }
            }
    }
    __syncthreads();

    unsigned short* tW = tAll + wave * 16 * ST;

    for (int t = blockIdx.x * 4 + wave; t < NN / 16; t += gridDim.x * 4) {
        const int n0 = t * 16;
        const int myRow = n0 + l15;
        const unsigned short* ph = hbf + (size_t)myRow * 64 + quad * 8;
        bf16x8 a0 = *(const bf16x8*)(ph);
        bf16x8 a1 = *(const bf16x8*)(ph + 32);
        bf16x8 a2, a3;
        {
            const float* pb = h_nb + (size_t)myRow * 64 + quad * 8;
            float4 v0 = *(const float4*)(pb);
            float4 v1 = *(const float4*)(pb + 4);
            float4 v2 = *(const float4*)(pb + 32);
            float4 v3 = *(const float4*)(pb + 36);
            unsigned int* pa2 = (unsigned int*)&a2;
            unsigned int* pa3 = (unsigned int*)&a3;
            pa2[0] = f2bf2u(v0.x, v0.y); pa2[1] = f2bf2u(v0.z, v0.w);
            pa2[2] = f2bf2u(v1.x, v1.y); pa2[3] = f2bf2u(v1.z, v1.w);
            pa3[0] = f2bf2u(v2.x, v2.y); pa3[1] = f2bf2u(v2.z, v2.w);
            pa3[2] = f2bf2u(v3.x, v3.y); pa3[3] = f2bf2u(v3.z, v3.w);
        }

        f32x4 acc[4];
#pragma unroll
        for (int nt = 0; nt < 4; ++nt) acc[nt] = (f32x4){0.f, 0.f, 0.f, 0.f};
        {
            const unsigned short* bBase = &w1T[l15 * SW + quad * 8];
#pragma unroll
            for (int nt = 0; nt < 4; ++nt) {
                const unsigned short* bb = bBase + nt * 16 * SW;
                acc[nt] = __builtin_amdgcn_mfma_f32_16x16x32_bf16(a0, *(const bf16x8*)(bb), acc[nt], 0, 0, 0);
                acc[nt] = __builtin_amdgcn_mfma_f32_16x16x32_bf16(a1, *(const bf16x8*)(bb + 32), acc[nt], 0, 0, 0);
                acc[nt] = __builtin_amdgcn_mfma_f32_16x16x32_bf16(a2, *(const bf16x8*)(bb + 64), acc[nt], 0, 0, 0);
                acc[nt] = __builtin_amdgcn_mfma_f32_16x16x32_bf16(a3, *(const bf16x8*)(bb + 96), acc[nt], 0, 0, 0);
            }
        }
#pragma unroll
        for (int nt = 0; nt < 4; ++nt) {
            int col = nt * 16 + l15;
#pragma unroll
            for (int r = 0; r < 4; ++r) {
                float v = acc[nt][r] + nb1s[col];
                tW[(quad * 4 + r) * ST + col] = f2bf(silu_f(v));
            }
        }
        f32x4 acc2[4];
#pragma unroll
        for (int nt = 0; nt < 4; ++nt) acc2[nt] = (f32x4){0.f, 0.f, 0.f, 0.f};
        {
            bf16x8 ax0 = *(const bf16x8*)&tW[l15 * ST + quad * 8];
            bf16x8 ax1 = *(const bf16x8*)&tW[l15 * ST + 32 + quad * 8];
            const unsigned short* bBase = &w2T[l15 * ST + quad * 8];
#pragma unroll
            for (int nt = 0; nt < 4; ++nt) {
                const unsigned short* bb = bBase + nt * 16 * ST;
                acc2[nt] = __builtin_amdgcn_mfma_f32_16x16x32_bf16(ax0, *(const bf16x8*)(bb), acc2[nt], 0, 0, 0);
                acc2[nt] = __builtin_amdgcn_mfma_f32_16x16x32_bf16(ax1, *(const bf16x8*)(bb + 32), acc2[nt], 0, 0, 0);
            }
        }
        float vals[4][4];
        float sum[4] = {0.f, 0.f, 0.f, 0.f}, ss[4] = {0.f, 0.f, 0.f, 0.f};
#pragma unroll
        for (int nt = 0; nt < 4; ++nt) {
            int col = nt * 16 + l15;
#pragma unroll
            for (int r = 0; r < 4; ++r) {
                float v = acc2[nt][r] + nb2s[col];
                float g = 0.5f * v * (1.0f + erff(v * 0.70710678118654752f));
                vals[nt][r] = g;
                sum[r] += g;
                ss[r] += g * g;
            }
        }
#pragma unroll
        for (int r = 0; r < 4; ++r) {
            float s1 = sum[r], s2 = ss[r];
            s1 += __shfl_xor(s1, 1); s2 += __shfl_xor(s2, 1);
            s1 += __shfl_xor(s1, 2); s2 += __shfl_xor(s2, 2);
            s1 += __shfl_xor(s1, 4); s2 += __shfl_xor(s2, 4);
            s1 += __shfl_xor(s1, 8); s2 += __shfl_xor(s2, 8);
            sum[r] = s1; ss[r] = s2;
        }
#pragma unroll
        for (int r = 0; r < 4; ++r) {
            float mean = sum[r] * (1.0f / 64.0f);
            float var  = ss[r] * (1.0f / 64.0f) - mean * mean;
            float rstd = rsqrtf(var + 1e-5f);
            int n = n0 + quad * 4 + r;
#pragma unroll
            for (int nt = 0; nt < 4; ++nt) {
                int col = nt * 16 + l15;
                float y = (vals[nt][r] - mean) * rstd * gs[col] + bs[col];
                if (DO_HEAD) tW[(quad * 4 + r) * ST + col] = f2bf(y);
                else hbf[(size_t)n * 64 + col] = f2bf(y);
            }
        }
        if (DO_HEAD) {
            f32x4 accH[2];
#pragma unroll
            for (int nt = 0; nt < 2; ++nt) accH[nt] = (f32x4){0.f, 0.f, 0.f, 0.f};
            bf16x8 ax0 = *(const bf16x8*)&tW[l15 * ST + quad * 8];
            bf16x8 ax1 = *(const bf16x8*)&tW[l15 * ST + 32 + quad * 8];
#pragma unroll
            for (int nt = 0; nt < 2; ++nt) {
                accH[nt] = __builtin_amdgcn_mfma_f32_16x16x32_bf16(ax0, b3[0][nt], accH[nt], 0, 0, 0);
                accH[nt] = __builtin_amdgcn_mfma_f32_16x16x32_bf16(ax1, b3[1][nt], accH[nt], 0, 0, 0);
            }
#pragma unroll
            for (int nt = 0; nt < 2; ++nt) {
                int col = nt * 16 + l15;
#pragma unroll
                for (int r = 0; r < 4; ++r)
                    out[(size_t)(n0 + quad * 4 + r) * 32 + col] = accH[nt][r] + obs[col];
            }
        }
    }
}

__global__ void init_h(const float* __restrict__ nf, unsigned short* __restrict__ hbf) {
    int i = blockIdx.x * 256 + threadIdx.x;
    if (i < NN * 64) hbf[i] = f2bf(nf[i]);
}
__global__ void init_x(const float* __restrict__ xyz, float4* __restrict__ x4) {
    int n = blockIdx.x * 256 + threadIdx.x;
    if (n < NN) {
        float4 v;
        v.x = xyz[n * 3 + 0]; v.y = xyz[n * 3 + 1]; v.z = xyz[n * 3 + 2]; v.w = 0.f;
        x4[n] = v;
    }
}

extern "C" void kernel_launch(void* const* d_in, const int* in_sizes, int n_in,
                              void* d_out, int out_size, void* d_ws, size_t ws_size,
                              hipStream_t stream)
{
    const float* node_feat = (const float*)d_in[0];
    const float* xyz   = (const float*)d_in[1];
    const int*   src   = (const int*)d_in[2];
    const int*   dst   = (const int*)d_in[3];
    const float* ew1   = (const float*)d_in[4];
    const float* eb1   = (const float*)d_in[5];
    const float* ew2   = (const float*)d_in[6];
    const float* eb2   = (const float*)d_in[7];
    const float* cw1   = (const float*)d_in[8];
    const float* cb1   = (const float*)d_in[9];
    const float* cw2   = (const float*)d_in[10];
    const float* nw1   = (const float*)d_in[11];
    const float* nb1   = (const float*)d_in[12];
    const float* nw2   = (const float*)d_in[13];
    const float* nb2   = (const float*)d_in[14];
    const float* ln_g  = (const float*)d_in[15];
    const float* ln_b  = (const float*)d_in[16];
    const float* out_w = (const float*)d_in[17];
    const float* out_b = (const float*)d_in[18];
    float* out = (float*)d_out;

    char* ws = (char*)d_ws;
    float* h_neigh = (float*)ws;                 ws += (size_t)NN * 64 * 4;
    unsigned short* hbf = (unsigned short*)ws;   ws += (size_t)NN * 64 * 2;
    unsigned short* Ys  = (unsigned short*)ws;   ws += (size_t)NN * 64 * 2;
    float* Yd     = (float*)ws;                  ws += (size_t)NN * 64 * 4;
    float4* xA    = (float4*)ws;                 ws += (size_t)NN * 16;
    float4* xB    = (float4*)ws;                 ws += (size_t)NN * 16;
    float* x_sum  = (float*)ws;                  ws += (size_t)NN * 3 * 4;
    int* rowptr   = (int*)ws;                    ws += (size_t)(NN + 1) * 4;
    int* chunkPtr = (int*)ws;                    ws += (size_t)(NN + 1) * 4;
    int* counts   = (int*)ws;                    ws += (size_t)NN * 4;   // reused as cursor
    int* srcS     = (int*)ws;                    ws += (size_t)NE * 4;
    int2* chunkTbl = (int2*)ws;                  ws += (size_t)(NN + NE / 16) * 8;
    int2* blockTot = (int2*)ws;                  ws += (size_t)SCAN_BLK * 8;

    hipMemsetAsync(counts, 0, (size_t)NN * 4, stream);
    init_h<<<(NN * 64 + 255) / 256, 256, 0, stream>>>(node_feat, hbf);
    init_x<<<(NN + 255) / 256, 256, 0, stream>>>(xyz, xA);
    hist_kernel<<<(NE + 255) / 256, 256, 0, stream>>>(dst, counts);
    scanA<<<SCAN_BLK, 256, 0, stream>>>(counts, blockTot);
    scanB<<<1, 128, 0, stream>>>(blockTot, rowptr, chunkPtr);
    scanC<<<SCAN_BLK, 256, 0, stream>>>(counts, blockTot, rowptr, counts, chunkPtr);
    scatter_kernel<<<(NE + 255) / 256, 256, 0, stream>>>(src, dst, counts, srcS);
    fill_chunks<<<(NN + 255) / 256, 256, 0, stream>>>(rowptr, chunkPtr, chunkTbl);

    // ---- layer 0 (computes x for layer 1)
    hipMemsetAsync(h_neigh, 0, (size_t)NN * 64 * 4, stream);
    hipMemsetAsync(x_sum, 0, (size_t)NN * 3 * 4, stream);
    prep_kernel<<<1024, 256, 0, stream>>>(hbf, ew1, eb1, Ys, Yd);
    edge6_kernel<true, 3><<<2048, 256, 0, stream>>>(
        xA, Ys, Yd, srcS, chunkTbl, chunkPtr + NN,
        ew1, ew2, eb2, cw1, cb1, cw2, h_neigh, x_sum);
    xupd<<<(NN + 255) / 256, 256, 0, stream>>>(x_sum, rowptr, xA, xB);
    node_kernel<false><<<1024, 256, 0, stream>>>(
        hbf, h_neigh, nw1, nb1, nw2, nb2, ln_g, ln_b, out_w, out_b, out);

    // ---- layer 1 (x output dead -> no coord head; head fused into node kernel)
    hipMemsetAsync(h_neigh, 0, (size_t)NN * 64 * 4, stream);
    prep_kernel<<<1024, 256, 0, stream>>>(hbf, ew1 + 129 * 64, eb1 + 64, Ys, Yd);
    edge6_kernel<false, 4><<<2048, 256, 0, stream>>>(
        xB, Ys, Yd, srcS, chunkTbl, chunkPtr + NN,
        ew1 + 129 * 64, ew2 + 64 * 64, eb2 + 64, cw1 + 64 * 64, cb1 + 64, cw2 + 64,
        h_neigh, nullptr);
    node_kernel<true><<<1024, 256, 0, stream>>>(
        hbf, h_neigh, nw1 + 128 * 64, nb1 + 64, nw2 + 64 * 64, nb2 + 64,
        ln_g, ln_b, out_w, out_b, out);
}